// Round 3
// baseline (854.064 us; speedup 1.0000x reference)
//
#include <hip/hip_runtime.h>

#define BB 512
#define NPG 50
#define EPG 60
#define DD 128
#define VV 100000
#define VPAD 100032
#define NSPLITS 4
#define FSCALE 12.0f
#define NN (BB*NPG)        // 25600
#define EE (BB*EPG)        // 30720
#define NDTOT (NN*DD)      // 3276800
#define NCB (VPAD/64)      // 1563
#define ASTR 140           // agg tile row stride (shorts): 280B -> ~2-way max bank aliasing on b128

typedef __attribute__((ext_vector_type(8))) short bfx8;
typedef __attribute__((ext_vector_type(4))) float f32x4;

__device__ __forceinline__ float sigmoidf_(float x){ return 1.f/(1.f+expf(-x)); }
__device__ __forceinline__ short f2bf(float f){
  union { float f; unsigned u; } v; v.f = f;
  unsigned r = v.u + 0x7FFF + ((v.u >> 16) & 1);
  return (short)(r >> 16);
}
__device__ __forceinline__ float bf2f(short s){
  union { unsigned u; float f; } v; v.u = ((unsigned)(unsigned short)s) << 16;
  return v.f;
}

// ---------- embn = l2norm(emb) in bf16, padded to VPAD rows ----------
__global__ __launch_bounds__(256) void k_embn(const float* __restrict__ emb, short* __restrict__ embn) {
  int row = blockIdx.x*4 + (threadIdx.x >> 6);
  int lane = threadIdx.x & 63;
  if (row >= VPAD) return;
  if (row >= VV) { embn[(size_t)row*DD+lane]=0; embn[(size_t)row*DD+64+lane]=0; return; }
  const float* r = emb + (size_t)row*DD;
  float a = r[lane], b = r[lane+64];
  float s = a*a + b*b;
  for (int off=32; off; off>>=1) s += __shfl_down(s, off);
  s = __shfl(s, 0);
  float inv = 1.0f/fmaxf(sqrtf(s), 1e-12f);
  embn[(size_t)row*DD+lane]    = f2bf(a*inv);
  embn[(size_t)row*DD+64+lane] = f2bf(b*inv);
}

// ---------- feat = l2norm(emb[iid]) -> x fp32 + xb bf16 ----------
__global__ __launch_bounds__(128) void k_gather(const int* __restrict__ iid, const float* __restrict__ emb,
                                                float* __restrict__ x, short* __restrict__ xb) {
  int n = blockIdx.x, d = threadIdx.x;
  int v = iid[n];
  float e = emb[(size_t)v*DD + d];
  __shared__ float red2[2];
  float ss = e*e;
  for (int off=32; off; off>>=1) ss += __shfl_down(ss, off);
  if ((d & 63)==0) red2[d>>6] = ss;
  __syncthreads();
  float inv = 1.f/fmaxf(sqrtf(red2[0]+red2[1]), 1e-12f);
  float f = e*inv;
  x[(size_t)n*DD + d] = f;
  xb[(size_t)n*DD + d] = f2bf(f);
}

// ---------- dt = max(edge_t)/SPLITS ----------
__global__ __launch_bounds__(256) void k_dt(const float* __restrict__ edge_t, float* __restrict__ dtp) {
  __shared__ float red[256];
  float m = -1e30f;
  for (int e = threadIdx.x; e < EE; e += 256) m = fmaxf(m, edge_t[e]);
  red[threadIdx.x] = m; __syncthreads();
  for (int s=128; s; s>>=1){ if ((int)threadIdx.x < s) red[threadIdx.x] = fmaxf(red[threadIdx.x], red[threadIdx.x+s]); __syncthreads(); }
  if (threadIdx.x==0) dtp[0] = red[0] / (float)NSPLITS;
}

// ---------- weight prep (bf16, [N][K] transposed layouts) ----------
__global__ void k_m12t(const float* __restrict__ W1, const float* __restrict__ W2,
                       const float* __restrict__ gw_ih, short* __restrict__ M12t) {
  int c = blockIdx.x, k = threadIdx.x;             // c<384, k<256
  const float* Wrow = (k < 128) ? (W1 + (size_t)k*128) : (W2 + (size_t)(k-128)*128);
  const float* grow = gw_ih + (size_t)c*256 + ((k < 128) ? 0 : 128);
  float s = 0.f;
  for (int j = 0; j < 128; ++j) s += Wrow[j]*grow[j];
  M12t[(size_t)c*256 + k] = f2bf(s);
}
__global__ void k_bfcopy(const float* __restrict__ src, short* __restrict__ dst) {
  size_t i = (size_t)blockIdx.x*blockDim.x + threadIdx.x;
  dst[i] = f2bf(src[i]);
}
__global__ void k_wrzt(const float* __restrict__ Wxr, const float* __restrict__ Wxz,
                       const float* __restrict__ Whr, const float* __restrict__ Whz,
                       short* __restrict__ Wrzt) {
  int c = blockIdx.x, k = threadIdx.x;             // 256 x 256
  float v;
  if (k < 128) v = (c < 128) ? Wxr[k*128+c] : Wxz[k*128+(c-128)];
  else         v = (c < 128) ? Whr[(k-128)*128+c] : Whz[(k-128)*128+(c-128)];
  Wrzt[(size_t)c*256 + k] = f2bf(v);
}
__global__ void k_wu2t(const float* __restrict__ Wxh, const float* __restrict__ Whh, short* __restrict__ Wu2t) {
  int c = blockIdx.x, k = threadIdx.x;             // 128 x 256
  float v = (k < 128) ? Wxh[k*128+c] : Whh[(k-128)*128+c];
  Wu2t[(size_t)c*256 + k] = f2bf(v);
}
__global__ void k_wt128(const float* __restrict__ W, short* __restrict__ Wt) {
  int c = blockIdx.x, k = threadIdx.x;             // 128 x 128
  Wt[(size_t)c*128 + k] = f2bf(W[(size_t)k*128 + c]);
}
__global__ void k_build_bias(const float* __restrict__ bxr, const float* __restrict__ bhr,
                             const float* __restrict__ bxz, const float* __restrict__ bhz,
                             const float* __restrict__ bxh, const float* __restrict__ bhh,
                             float* __restrict__ brz, float* __restrict__ bu) {
  int t = threadIdx.x;
  if (t < 128) brz[t] = bxr[t] + bhr[t];
  else if (t < 256) brz[t] = bxz[t-128] + bhz[t-128];
  else bu[t-256] = bxh[t-256] + bhh[t-256];
}

// ---------- per-group stage-C means (gather/CSR form) -> ABb bf16 ----------
__global__ __launch_bounds__(256) void k_grp_mean(const int* __restrict__ src, const int* __restrict__ dst,
                                                  const float* __restrict__ ew, const float* __restrict__ feat,
                                                  short* __restrict__ ABb) {
  __shared__ int stl[EPG];
  __shared__ float wl[EPG];
  __shared__ int rp1[NPG+1], rp2[NPG+1];
  __shared__ short ci1[EPG], ci2[EPG];     // j | e<<8
  __shared__ float den1[NPG], den2[NPG];
  __shared__ int c1[NPG], c2[NPG];
  int b = blockIdx.x, tid = threadIdx.x;
  int nb = b*NPG, eb = b*EPG;
  if (tid < EPG) { stl[tid] = (src[eb+tid]-nb) | ((dst[eb+tid]-nb)<<16); wl[tid] = ew[eb+tid]; }
  __syncthreads();
  if (tid < NPG) {
    int a = 0, bc = 0; float dA = 0.f, dB = 0.f;
    for (int e = 0; e < EPG; ++e) {
      int st = stl[e]; int s = st & 0xffff, t = st >> 16;
      if (t == tid) { a++;  dA += wl[e]; }
      if (s == tid) { bc++; dB += wl[e]; }
    }
    c1[tid] = a; c2[tid] = bc;
    den1[tid] = (dA == 0.f) ? 1.f : dA;
    den2[tid] = (dB == 0.f) ? 1.f : dB;
  }
  __syncthreads();
  if (tid == 0) { int acc = 0; for (int n = 0; n < NPG; ++n) { rp1[n] = acc; acc += c1[n]; } rp1[NPG] = acc; }
  if (tid == 1) { int acc = 0; for (int n = 0; n < NPG; ++n) { rp2[n] = acc; acc += c2[n]; } rp2[NPG] = acc; }
  __syncthreads();
  if (tid < NPG) {
    int w1 = rp1[tid], w2 = rp2[tid];
    for (int e = 0; e < EPG; ++e) {
      int st = stl[e]; int s = st & 0xffff, t = st >> 16;
      if (t == tid) ci1[w1++] = (short)(s | (e<<8));
      if (s == tid) ci2[w2++] = (short)(t | (e<<8));
    }
  }
  __syncthreads();
  const float* fg = feat + (size_t)nb*128;
  for (int i = tid; i < NPG*128; i += 256) {
    int n = i >> 7, d = i & 127;
    float a1 = 0.f, a2 = 0.f;
    for (int idx = rp1[n]; idx < rp1[n+1]; ++idx) {
      int v = ci1[idx]; int j = v & 255, e = v >> 8;
      a1 += fg[j*128 + d] * wl[e];
    }
    for (int idx = rp2[n]; idx < rp2[n+1]; ++idx) {
      int v = ci2[idx]; int j = v & 255, e = v >> 8;
      a2 += fg[j*128 + d] * wl[e];
    }
    ABb[(size_t)(nb+n)*256 + d]       = f2bf(a1/den1[n]);
    ABb[(size_t)(nb+n)*256 + 128 + d] = f2bf(a2/den2[n]);
  }
}

// ---------- GRU + l2norm (writes x only; h starts equal to x in ODE) ----------
__global__ __launch_bounds__(128) void k_gru(const float* __restrict__ gi, const float* __restrict__ gh,
                                             float* __restrict__ x) {
  int n = blockIdx.x, d = threadIdx.x;
  const float* gin = gi + (size_t)n*384;
  const float* ghn = gh + (size_t)n*384;
  float ir = gin[d], iz = gin[128+d], ig = gin[256+d];
  float hr = ghn[d], hz = ghn[128+d], hg = ghn[256+d];
  float f0 = x[(size_t)n*DD + d];
  float r = sigmoidf_(ir + hr);
  float z = sigmoidf_(iz + hz);
  float g = tanhf(ig + r*hg);
  float f = (1.f - z)*g + z*f0;
  __shared__ float red2[2];
  float ss = f*f;
  for (int off=32; off; off>>=1) ss += __shfl_down(ss, off);
  if ((d & 63)==0) red2[d>>6] = ss;
  __syncthreads();
  float inv = 1.f/fmaxf(sqrtf(red2[0]+red2[1]), 1e-12f);
  x[(size_t)n*DD + d] = f*inv;
}

// ---------- fused ODE: gather/CSR form, 8 waves, all 4 splits in LDS ----------
// x read from global (L1-resident per group); h in LDS fp32; rh staged bf16;
// z gates kept in registers of waves 4-7 (GEMM1 z-cols == GEMM2 out-cols).
__global__ __launch_bounds__(512, 2) void k_ode_fused(
    const int* __restrict__ src, const int* __restrict__ dst,
    const float* __restrict__ edge_t, const float* __restrict__ node_t,
    const float* __restrict__ dtp,
    float* __restrict__ x, short* __restrict__ fbb,
    const short* __restrict__ Wrzt, const short* __restrict__ Wu2t,
    const float* __restrict__ brz, const float* __restrict__ bu)
{
  __shared__ __align__(16) float hl[NPG*128];        // 25600 B
  __shared__ __align__(16) short rhb[NPG*ASTR];      // 14000 B
  __shared__ __align__(16) short aggX[64*ASTR];      // 17920 B
  __shared__ __align__(16) short aggH[64*ASTR];      // 17920 B
  __shared__ int   rp[NPG+1];
  __shared__ short ci[2*EPG];                        // j | e<<8
  __shared__ int   cnt[NPG];
  __shared__ int   stl[EPG];
  __shared__ float etl[EPG];
  __shared__ float ntl[NPG];
  __shared__ float disl[NPG];
  __shared__ unsigned long long actm_s;
  __shared__ float red8[8];

  const int b = blockIdx.x, tid = threadIdx.x;
  const int nb = b*NPG, eb = b*EPG;
  const int wave = tid>>6, lane = tid&63, quad = lane>>4, l16 = lane&15;
  const float dtv = dtp[0];
  const float* xg = x + (size_t)nb*128;

  for (int i = tid; i < NPG*32; i += 512)
    ((float4*)hl)[i] = ((const float4*)xg)[i];
  if (tid < EPG) { stl[tid] = (src[eb+tid]-nb) | ((dst[eb+tid]-nb)<<16); etl[tid] = edge_t[eb+tid]; }
  if (tid >= 64 && tid < 64+NPG) ntl[tid-64] = node_t[nb+tid-64];
  for (int i = tid; i < 14*ASTR; i += 512) { aggX[NPG*ASTR + i] = 0; aggH[NPG*ASTR + i] = 0; }
  __syncthreads();

  // ---- static incidence CSR (both directions; self-edges masked at use) ----
  if (tid < NPG) {
    int c = 0;
    for (int e = 0; e < EPG; ++e) {
      int st = stl[e]; int s = st & 0xffff, t = st >> 16;
      c += (s==tid) + (t==tid);
    }
    cnt[tid] = c;
  }
  __syncthreads();
  if (tid == 0) { int acc = 0; for (int n = 0; n < NPG; ++n) { rp[n] = acc; acc += cnt[n]; } rp[NPG] = acc; }
  __syncthreads();
  if (tid < NPG) {
    int w = rp[tid];
    for (int e = 0; e < EPG; ++e) {
      int st = stl[e]; int s = st & 0xffff, t = st >> 16;
      if (t == tid) ci[w++] = (short)(s | (e<<8));
      if (s == tid) ci[w++] = (short)(t | (e<<8));
    }
  }
  __syncthreads();

  float zreg[4][2][4];   // z gates, waves 4-7 only (static-indexed via full unroll)

  for (int ks = 0; ks < NSPLITS; ++ks) {
    const float t = (float)ks * dtv;
    // --- activity mask + deg/dis (wave 0) ---
    if (wave == 0) {
      bool p = false;
      if (lane < EPG) {
        int st = stl[lane]; int s = st & 0xffff, tt = st >> 16;
        p = (etl[lane] <= t) && (ntl[s] >= t) && (ntl[tt] >= t) && (s != tt);
      }
      unsigned long long m = __ballot(p);
      if (lane == 0) actm_s = m;
      if (lane < NPG) {
        float deg = 0.f;
        for (int idx = rp[lane]; idx < rp[lane+1]; ++idx) {
          int e = ((int)ci[idx]) >> 8;
          deg += (float)((m >> e) & 1ULL);
        }
        disl[lane] = rsqrtf(fmaxf(deg, 1.f));
      }
    }
    __syncthreads();
    const unsigned long long actm = actm_s;

    // --- gather agg_x (global/L1) + agg_h (LDS) -> bf16 tiles, register acc ---
    for (int i = tid; i < NPG*128; i += 512) {
      int n = i >> 7, d = i & 127;
      float ax = 0.f, ah = 0.f;
      for (int idx = rp[n]; idx < rp[n+1]; ++idx) {
        int v = ci[idx]; int j = v & 255, e = v >> 8;
        if ((actm >> e) & 1ULL) {
          float dj = disl[j];
          ax += xg[j*128 + d] * dj;
          ah += hl[j*128 + d] * dj;
        }
      }
      float dn = disl[n];
      aggX[n*ASTR + d] = f2bf(ax*dn);
      aggH[n*ASTR + d] = f2bf(ah*dn);
    }
    __syncthreads();

    // --- GEMM1: [64x256] @ Wrzt^T -> sigmoid; rh (waves 0-3) / z regs (waves 4-7) ---
    {
      f32x4 acc[4][2] = {{{0.f,0.f,0.f,0.f},{0.f,0.f,0.f,0.f}},
                         {{0.f,0.f,0.f,0.f},{0.f,0.f,0.f,0.f}},
                         {{0.f,0.f,0.f,0.f},{0.f,0.f,0.f,0.f}},
                         {{0.f,0.f,0.f,0.f},{0.f,0.f,0.f,0.f}}};
      for (int k0 = 0; k0 < 256; k0 += 32) {
        const short* Ab = (k0 < 128) ? aggX : aggH;
        const int kk = (k0 & 127) + quad*8;
        bfx8 af[4];
#pragma unroll
        for (int m = 0; m < 4; ++m) af[m] = *(const bfx8*)&Ab[(m*16+l16)*ASTR + kk];
#pragma unroll
        for (int n = 0; n < 2; ++n) {
          const int bn = (wave*2+n)*16 + l16;
          bfx8 bf = *(const bfx8*)&Wrzt[(size_t)bn*256 + k0 + quad*8];
#pragma unroll
          for (int m = 0; m < 4; ++m)
            acc[m][n] = __builtin_amdgcn_mfma_f32_16x16x32_bf16(af[m], bf, acc[m][n], 0, 0, 0);
        }
      }
#pragma unroll
      for (int n = 0; n < 2; ++n) {
        const int col = (wave*2+n)*16 + l16;
        const float bb = brz[col];
#pragma unroll
        for (int m = 0; m < 4; ++m)
#pragma unroll
          for (int r = 0; r < 4; ++r) {
            const int row = m*16 + quad*4 + r;
            float s = sigmoidf_(acc[m][n][r] + bb);
            if (wave < 4) {
              if (row < NPG) rhb[row*ASTR + col] = f2bf(s * hl[row*128 + col]);
            } else {
              zreg[m][n][r] = s;
            }
          }
      }
    }
    __syncthreads();

    // --- gather agg_rh -> aggH ---
    for (int i = tid; i < NPG*128; i += 512) {
      int n = i >> 7, d = i & 127;
      float ar = 0.f;
      for (int idx = rp[n]; idx < rp[n+1]; ++idx) {
        int v = ci[idx]; int j = v & 255, e = v >> 8;
        if ((actm >> e) & 1ULL) ar += bf2f(rhb[j*ASTR + d]) * disl[j];
      }
      aggH[n*ASTR + d] = f2bf(ar*disl[n]);
    }
    __syncthreads();

    // --- GEMM2 (waves 4-7): [64x256] @ Wu2t^T -> tanh -> h update (z from regs) ---
    if (wave >= 4) {
      f32x4 acc2[4][2] = {{{0.f,0.f,0.f,0.f},{0.f,0.f,0.f,0.f}},
                          {{0.f,0.f,0.f,0.f},{0.f,0.f,0.f,0.f}},
                          {{0.f,0.f,0.f,0.f},{0.f,0.f,0.f,0.f}},
                          {{0.f,0.f,0.f,0.f},{0.f,0.f,0.f,0.f}}};
      for (int k0 = 0; k0 < 256; k0 += 32) {
        const short* Ab = (k0 < 128) ? aggX : aggH;
        const int kk = (k0 & 127) + quad*8;
        bfx8 af[4];
#pragma unroll
        for (int m = 0; m < 4; ++m) af[m] = *(const bfx8*)&Ab[(m*16+l16)*ASTR + kk];
#pragma unroll
        for (int n = 0; n < 2; ++n) {
          const int col2 = ((wave-4)*2+n)*16 + l16;
          bfx8 bf = *(const bfx8*)&Wu2t[(size_t)col2*256 + k0 + quad*8];
#pragma unroll
          for (int m = 0; m < 4; ++m)
            acc2[m][n] = __builtin_amdgcn_mfma_f32_16x16x32_bf16(af[m], bf, acc2[m][n], 0, 0, 0);
        }
      }
#pragma unroll
      for (int n = 0; n < 2; ++n) {
        const int col2 = ((wave-4)*2+n)*16 + l16;
        const float bb = bu[col2];
#pragma unroll
        for (int m = 0; m < 4; ++m)
#pragma unroll
          for (int r = 0; r < 4; ++r) {
            const int row = m*16 + quad*4 + r;
            if (row < NPG && ntl[row] >= t) {
              float hv = hl[row*128 + col2];
              float uu = tanhf(acc2[m][n][r] + bb);
              hl[row*128 + col2] = hv + dtv*(1.f - zreg[m][n][r])*(uu - hv);
            }
          }
      }
    }
    __syncthreads();
  }

  // --- final l2norm of h -> x (fp32) + fbb (bf16), 4 rows/iter ---
  for (int rp_ = 0; rp_ < NPG; rp_ += 4) {
    const int r = rp_ + (tid>>7);
    const int d = tid & 127;
    float v = (r < NPG) ? hl[r*128 + d] : 0.f;
    float ss = v*v;
    for (int off=32; off; off>>=1) ss += __shfl_down(ss, off);
    if (lane == 0) red8[wave] = ss;
    __syncthreads();
    int g = tid>>7;
    float inv = 1.f/fmaxf(sqrtf(red8[2*g]+red8[2*g+1]), 1e-12f);
    if (r < NPG) {
      float f = v*inv;
      x[(size_t)(nb+r)*128 + d] = f;
      fbb[(size_t)(nb+r)*128 + d] = f2bf(f);
    }
    __syncthreads();
  }
}

// ---------- bf16 MFMA GEMM: 64x64 block tile, 4 waves, 16x16x32 ----------
// A [M][K] bf16 (lda), Bt [N][K] bf16 (ldbt). modes:
// 0: C = A@B + bias (fp32, ldc)                        grid (colblk, rowblk)
// 4: logits LSE pass: per-64col-block (max,sumexp) partials only (no store)
//    grid (12504 linear, XCD-swizzled so one XCD owns all 8 rowblks of a cb)
// 5: logits store pass: out[r][c] = acc - bias[r]  (bias = lse); same grid
__global__ __launch_bounds__(256) void gemm_mfma(
    const short* __restrict__ A, int lda,
    const short* __restrict__ Bt, int ldbt,
    const float* __restrict__ bias,
    float* __restrict__ C, int ldc,
    int K, int mode,
    float* __restrict__ outp, float* __restrict__ pmax, float* __restrict__ psum)
{
  __shared__ short As[64*40];
  __shared__ short Bs[64*40];
  const int tid = threadIdx.x;
  const int wave = tid >> 6, lane = tid & 63;
  const int wr = wave >> 1, wc = wave & 1;
  const int quad = lane >> 4, l16 = lane & 15;
  int rb, cb;
  if (mode >= 4) {
    int t = (blockIdx.x & 7)*1563 + (blockIdx.x >> 3);   // 12504 = 8*1563
    rb = t & 7; cb = t >> 3;
  } else { rb = blockIdx.y; cb = blockIdx.x; }
  const int row0 = rb*64, col0 = cb*64;
  f32x4 acc[2][2] = {{{0.f,0.f,0.f,0.f},{0.f,0.f,0.f,0.f}},{{0.f,0.f,0.f,0.f},{0.f,0.f,0.f,0.f}}};
  const int sm = tid >> 2, skq = tid & 3;
  const short* Ap = A + (size_t)(row0+sm)*lda + skq*8;
  const short* Bp = Bt + (size_t)(col0+sm)*ldbt + skq*8;
  for (int k0 = 0; k0 < K; k0 += 32) {
    *(bfx8*)&As[sm*40 + skq*8] = *(const bfx8*)(Ap + k0);
    *(bfx8*)&Bs[sm*40 + skq*8] = *(const bfx8*)(Bp + k0);
    __syncthreads();
    bfx8 a0 = *(bfx8*)&As[(wr*32 + l16)*40 + quad*8];
    bfx8 a1 = *(bfx8*)&As[(wr*32 + 16 + l16)*40 + quad*8];
    bfx8 b0 = *(bfx8*)&Bs[(wc*32 + l16)*40 + quad*8];
    bfx8 b1 = *(bfx8*)&Bs[(wc*32 + 16 + l16)*40 + quad*8];
    acc[0][0] = __builtin_amdgcn_mfma_f32_16x16x32_bf16(a0, b0, acc[0][0], 0, 0, 0);
    acc[0][1] = __builtin_amdgcn_mfma_f32_16x16x32_bf16(a0, b1, acc[0][1], 0, 0, 0);
    acc[1][0] = __builtin_amdgcn_mfma_f32_16x16x32_bf16(a1, b0, acc[1][0], 0, 0, 0);
    acc[1][1] = __builtin_amdgcn_mfma_f32_16x16x32_bf16(a1, b1, acc[1][1], 0, 0, 0);
    __syncthreads();
  }

  if (mode == 0) {
#pragma unroll
    for (int i = 0; i < 2; ++i)
#pragma unroll
      for (int j = 0; j < 2; ++j) {
        int gc = col0 + wc*32 + j*16 + l16;
        float bb = bias ? bias[gc] : 0.f;
#pragma unroll
        for (int r = 0; r < 4; ++r) {
          int gr = row0 + wr*32 + i*16 + quad*4 + r;
          C[(size_t)gr*ldc + gc] = acc[i][j][r] + bb;
        }
      }
  } else if (mode == 4) { // LSE partials: max-reduce first, then sum(exp)
    __shared__ float pm[64][2], ps[64][2];
    int c0 = col0 + wc*32 + l16;
    int c1 = c0 + 16;
#pragma unroll
    for (int i = 0; i < 2; ++i) {
#pragma unroll
      for (int r = 0; r < 4; ++r) {
        int rloc = wr*32 + i*16 + quad*4 + r;
        float v0 = (c0 < VV) ? acc[i][0][r] : -1e30f;
        float v1 = (c1 < VV) ? acc[i][1][r] : -1e30f;
        float m = fmaxf(v0, v1);
#pragma unroll
        for (int off = 1; off < 16; off <<= 1) m = fmaxf(m, __shfl_xor(m, off));
        float s = expf(v0 - m) + expf(v1 - m);
#pragma unroll
        for (int off = 1; off < 16; off <<= 1) s += __shfl_xor(s, off);
        if (l16 == 0) { pm[rloc][wc] = m; ps[rloc][wc] = s; }
      }
    }
    __syncthreads();
    if (tid < 64) {
      float m0 = pm[tid][0], m1 = pm[tid][1];
      float s0 = ps[tid][0], s1 = ps[tid][1];
      float M = fmaxf(m0, m1);
      float S = s0*expf(m0 - M) + s1*expf(m1 - M);
      pmax[(size_t)(row0 + tid)*NCB + cb] = M;
      psum[(size_t)(row0 + tid)*NCB + cb] = S;
    }
  } else { // mode 5: out = acc - lse[row]   (bias = lse)
#pragma unroll
    for (int i = 0; i < 2; ++i) {
#pragma unroll
      for (int r = 0; r < 4; ++r) {
        int gr = row0 + wr*32 + i*16 + quad*4 + r;
        float l = bias[gr];
#pragma unroll
        for (int j = 0; j < 2; ++j) {
          int gc = col0 + wc*32 + j*16 + l16;
          if (gc < VV) outp[(size_t)gr*VV + gc] = acc[i][j][r] - l;
        }
      }
    }
  }
}

// ---------- attention readout + W_sr + l2norm -> srvb bf16 (pre-scaled) ----------
__global__ __launch_bounds__(128) void k_attn(const float* __restrict__ fb, const float* __restrict__ U,
                                              const float* __restrict__ lv, const float* __restrict__ We,
                                              const float* __restrict__ W_sr, short* __restrict__ srvb) {
  int b = blockIdx.x, d = threadIdx.x;
  __shared__ float sc[NPG];
  __shared__ float lastv[DD], srg[DD];
  __shared__ float red2[2];
  const float* Ub  = U  + (size_t)b*NPG*DD;
  const float* lvb = lv + (size_t)b*DD;
  if (d < 64) {
    for (int i=0;i<NPG;++i) {
      float e = We[d]   * sigmoidf_(Ub[i*DD + d]      + lvb[d]) +
                We[d+64]* sigmoidf_(Ub[i*DD + 64 + d] + lvb[d+64]);
      for (int off=32; off; off>>=1) e += __shfl_down(e, off);
      if (d==0) sc[i] = e;
    }
  }
  __syncthreads();
  if (d < 64) {
    float v = (d < NPG) ? sc[d] : -1e30f;
    float m = v;
    for (int off=1; off<64; off<<=1) m = fmaxf(m, __shfl_xor(m, off));
    float ex = (d < NPG) ? expf(v - m) : 0.f;
    float s = ex;
    for (int off=1; off<64; off<<=1) s += __shfl_xor(s, off);
    if (d < NPG) sc[d] = ex/s;
  }
  __syncthreads();
  const float* fbb = fb + (size_t)b*NPG*DD;
  float lastd = fbb[(NPG-1)*DD + d];
  float sg = 0.f;
  for (int i=0;i<NPG;++i) sg += fbb[i*DD + d]*sc[i];
  lastv[d] = lastd; srg[d] = sg;
  __syncthreads();
  float acc = 0.f;
  for (int k=0;k<DD;++k) acc += lastv[k]*W_sr[k*DD + d];
  for (int k=0;k<DD;++k) acc += srg[k]*W_sr[(DD+k)*DD + d];
  float ss = acc*acc;
  for (int off=32; off; off>>=1) ss += __shfl_down(ss, off);
  if ((d & 63)==0) red2[d>>6] = ss;
  __syncthreads();
  float inv = 1.f/fmaxf(sqrtf(red2[0]+red2[1]), 1e-12f);
  srvb[(size_t)b*DD + d] = f2bf(FSCALE*acc*inv);
}

__global__ __launch_bounds__(256) void k_lse(const float* __restrict__ pmax, const float* __restrict__ psum,
                                             float* __restrict__ lse) {
  int r = blockIdx.x, tid = threadIdx.x;
  float m = -1e30f, s = 0.f;
  for (int cb = tid; cb < NCB; cb += 256) {
    float m2 = pmax[(size_t)r*NCB + cb], s2 = psum[(size_t)r*NCB + cb];
    float M = fmaxf(m, m2);
    s = s*expf(m - M) + s2*expf(m2 - M);
    m = M;
  }
  __shared__ float ms[256], ssh[256];
  ms[tid] = m; ssh[tid] = s; __syncthreads();
  for (int st=128; st; st>>=1) {
    if (tid < st) {
      float m2 = ms[tid+st], s2 = ssh[tid+st];
      float M = fmaxf(ms[tid], m2);
      ssh[tid] = ssh[tid]*expf(ms[tid]-M) + s2*expf(m2-M);
      ms[tid] = M;
    }
    __syncthreads();
  }
  if (tid==0) lse[r] = ms[0] + logf(ssh[0]);
}

extern "C" void kernel_launch(void* const* d_in, const int* in_sizes, int n_in,
                              void* d_out, int out_size, void* d_ws, size_t ws_size,
                              hipStream_t stream) {
  (void)in_sizes; (void)n_in; (void)out_size; (void)ws_size;
  const int*   iid    = (const int*)  d_in[0];
  const int*   src    = (const int*)  d_in[1];
  const int*   dst    = (const int*)  d_in[2];
  const float* edge_w = (const float*)d_in[3];
  const float* edge_t = (const float*)d_in[4];
  const float* node_t = (const float*)d_in[5];
  const float* emb    = (const float*)d_in[6];
  const float* W1     = (const float*)d_in[7];
  const float* W2     = (const float*)d_in[8];
  const float* gw_ih  = (const float*)d_in[9];
  const float* gw_hh  = (const float*)d_in[10];
  const float* gb_ih  = (const float*)d_in[11];
  const float* gb_hh  = (const float*)d_in[12];
  const float* Wxr = (const float*)d_in[13]; const float* bxr = (const float*)d_in[14];
  const float* Wxz = (const float*)d_in[15]; const float* bxz = (const float*)d_in[16];
  const float* Wxh = (const float*)d_in[17]; const float* bxh = (const float*)d_in[18];
  const float* Whr = (const float*)d_in[19]; const float* bhr = (const float*)d_in[20];
  const float* Whz = (const float*)d_in[21]; const float* bhz = (const float*)d_in[22];
  const float* Whh = (const float*)d_in[23]; const float* bhh = (const float*)d_in[24];
  const float* Wu  = (const float*)d_in[25];
  const float* Wv  = (const float*)d_in[26]; const float* bv  = (const float*)d_in[27];
  const float* We  = (const float*)d_in[28];
  const float* W_sr= (const float*)d_in[29];

  float* ws  = (float*)d_ws;
  float* out = (float*)d_out;

  // ---- workspace layout (float units; shorts live in float-sized slots) ----
  short* embn = (short*)ws;                         // VPAD*128 shorts = 6,402,048 fl
  float* pmax = ws + 6402048;                       // 512*1563 = 800,256
  float* psum = pmax + 800256;                      // 800,256
  short* M12t = (short*)(psum + 800256);            // 384*256 sh = 49,152 fl
  short* gwhhb= (short*)(psum + 800256 + 49152);    // 384*128 sh = 24,576 fl
  short* Wrzt = (short*)(psum + 800256 + 73728);    // 256*256 sh = 32,768 fl
  short* Wu2t = (short*)(psum + 800256 + 106496);   // 128*256 sh = 16,384 fl
  short* Wut  = (short*)(psum + 800256 + 122880);   // 128*128 sh = 8,192 fl
  short* Wvt  = (short*)(psum + 800256 + 131072);   // 8,192 fl
  float* brz  = psum + 800256 + 139264;             // 256
  float* bu   = brz + 256;                          // 128
  float* lv   = bu + 128;                           // 65,536
  float* dtp  = lv + 65536;                         // 4
  float* lse  = dtp + 4;                            // 512
  short* srvb = (short*)(lse + 512);                // 512*128 sh = 32,768 fl

  // ---- d_out as scratch until the logits pass (51.2M floats) ----
  short* ABb = (short*)out;                         // 25600*256 sh (3.28M fl)
  float* x   = out + (size_t) 4*1024*1024;          // 3.28M
  float* gi  = out + (size_t)20*1024*1024;          // 9.83M
  float* gh  = out + (size_t)30*1024*1024;          // 9.83M
  float* U   = out + (size_t)20*1024*1024;          // reuse gi after GRU
  short* xb  = (short*)(out + (size_t)40*1024*1024);// 25600*128 sh (1.64M fl)
  short* fbb = (short*)(out + (size_t)42*1024*1024);// 1.64M fl

  // ---- prep ----
  k_embn<<<VPAD/4, 256, 0, stream>>>(emb, embn);
  k_gather<<<NN, 128, 0, stream>>>(iid, emb, x, xb);
  k_dt<<<1, 256, 0, stream>>>(edge_t, dtp);
  k_m12t<<<384, 256, 0, stream>>>(W1, W2, gw_ih, M12t);
  k_bfcopy<<<384, 128, 0, stream>>>(gw_hh, gwhhb);
  k_wrzt<<<256, 256, 0, stream>>>(Wxr, Wxz, Whr, Whz, Wrzt);
  k_wu2t<<<128, 256, 0, stream>>>(Wxh, Whh, Wu2t);
  k_wt128<<<128, 128, 0, stream>>>(Wu, Wut);
  k_wt128<<<128, 128, 0, stream>>>(Wv, Wvt);
  k_build_bias<<<1, 384, 0, stream>>>(bxr, bhr, bxz, bhz, bxh, bhh, brz, bu);

  // ---- stage C (gather form) ----
  k_grp_mean<<<BB, 256, 0, stream>>>(src, dst, edge_w, x, ABb);

  // ---- GRU ----
  gemm_mfma<<<dim3(6,400), 256, 0, stream>>>(ABb, 256, M12t, 256, gb_ih, gi, 384, 256, 0,
      nullptr, nullptr, nullptr);
  gemm_mfma<<<dim3(6,400), 256, 0, stream>>>(xb, 128, gwhhb, 128, gb_hh, gh, 384, 128, 0,
      nullptr, nullptr, nullptr);
  k_gru<<<NN, 128, 0, stream>>>(gi, gh, x);

  // ---- ODE (gather/CSR, 8 waves, all 4 splits in LDS; outputs l2norm'd x + fbb) ----
  k_ode_fused<<<BB, 512, 0, stream>>>(src, dst, edge_t, node_t, dtp, x, fbb, Wrzt, Wu2t, brz, bu);

  // ---- attention ----
  gemm_mfma<<<dim3(2,400), 256, 0, stream>>>(fbb, 128, Wut, 128, nullptr, U, 128, 128, 0,
      nullptr, nullptr, nullptr);
  gemm_mfma<<<dim3(2,8), 256, 0, stream>>>(fbb + (size_t)(NPG-1)*DD, NPG*DD, Wvt, 128, bv, lv, 128, 128, 0,
      nullptr, nullptr, nullptr);
  k_attn<<<BB, 128, 0, stream>>>(x, U, lv, We, W_sr, srvb);

  // ---- logits: pass 1 (LSE partials) -> lse -> pass 2 (store acc - lse) ----
  gemm_mfma<<<dim3(8*NCB), 256, 0, stream>>>(srvb, 128, embn, 128, nullptr, nullptr, 0, 128, 4,
      nullptr, pmax, psum);
  k_lse<<<BB, 256, 0, stream>>>(pmax, psum, lse);
  gemm_mfma<<<dim3(8*NCB), 256, 0, stream>>>(srvb, 128, embn, 128, lse, nullptr, 0, 128, 5,
      out, nullptr, nullptr);
}

// Round 4
// 709.929 us; speedup vs baseline: 1.2030x; 1.2030x over previous
//
#include <hip/hip_runtime.h>

#define BB 512
#define NPG 50
#define EPG 60
#define DD 128
#define VV 100000
#define VPAD 100032
#define NSPLITS 4
#define FSCALE 12.0f
#define NN (BB*NPG)        // 25600
#define EE (BB*EPG)        // 30720
#define NCB (VPAD/64)      // 1563
#define HSTR 132           // hl fp32 row stride (132%8=4 words -> bank spread, 16B-aligned rows)
#define RSTR 136           // rhb bf16 row stride
#define TSTR 72            // T1t bf16 row stride
#define MSTR 72            // Mp  bf16 row stride

typedef __attribute__((ext_vector_type(8))) short bfx8;
typedef __attribute__((ext_vector_type(4))) float f32x4;

__device__ __forceinline__ float sigmoidf_(float x){ return 1.f/(1.f+expf(-x)); }
__device__ __forceinline__ short f2bf(float f){
  union { float f; unsigned u; } v; v.f = f;
  unsigned r = v.u + 0x7FFF + ((v.u >> 16) & 1);
  return (short)(r >> 16);
}
__device__ __forceinline__ float bf2f(short s){
  union { unsigned u; float f; } v; v.u = ((unsigned)(unsigned short)s) << 16;
  return v.f;
}
__device__ __forceinline__ unsigned cvtpk_(float lo, float hi){
  unsigned r; asm("v_cvt_pk_bf16_f32 %0, %1, %2" : "=v"(r) : "v"(lo), "v"(hi)); return r;
}
__device__ __forceinline__ bfx8 pack8(float4 a, float4 b){
  union { bfx8 v; unsigned u[4]; } w;
  w.u[0] = cvtpk_(a.x, a.y); w.u[1] = cvtpk_(a.z, a.w);
  w.u[2] = cvtpk_(b.x, b.y); w.u[3] = cvtpk_(b.z, b.w);
  return w.v;
}

// ---------- embn = l2norm(emb) in bf16, padded to VPAD rows ----------
__global__ __launch_bounds__(256) void k_embn(const float* __restrict__ emb, short* __restrict__ embn) {
  int row = blockIdx.x*4 + (threadIdx.x >> 6);
  int lane = threadIdx.x & 63;
  if (row >= VPAD) return;
  if (row >= VV) { embn[(size_t)row*DD+lane]=0; embn[(size_t)row*DD+64+lane]=0; return; }
  const float* r = emb + (size_t)row*DD;
  float a = r[lane], b = r[lane+64];
  float s = a*a + b*b;
  for (int off=32; off; off>>=1) s += __shfl_down(s, off);
  s = __shfl(s, 0);
  float inv = 1.0f/fmaxf(sqrtf(s), 1e-12f);
  embn[(size_t)row*DD+lane]    = f2bf(a*inv);
  embn[(size_t)row*DD+64+lane] = f2bf(b*inv);
}

// ---------- feat = l2norm(emb[iid]) -> x fp32 + xb bf16 ----------
__global__ __launch_bounds__(128) void k_gather(const int* __restrict__ iid, const float* __restrict__ emb,
                                                float* __restrict__ x, short* __restrict__ xb) {
  int n = blockIdx.x, d = threadIdx.x;
  int v = iid[n];
  float e = emb[(size_t)v*DD + d];
  __shared__ float red2[2];
  float ss = e*e;
  for (int off=32; off; off>>=1) ss += __shfl_down(ss, off);
  if ((d & 63)==0) red2[d>>6] = ss;
  __syncthreads();
  float inv = 1.f/fmaxf(sqrtf(red2[0]+red2[1]), 1e-12f);
  float f = e*inv;
  x[(size_t)n*DD + d] = f;
  xb[(size_t)n*DD + d] = f2bf(f);
}

// ---------- dt = max(edge_t)/SPLITS ----------
__global__ __launch_bounds__(256) void k_dt(const float* __restrict__ edge_t, float* __restrict__ dtp) {
  __shared__ float red[256];
  float m = -1e30f;
  for (int e = threadIdx.x; e < EE; e += 256) m = fmaxf(m, edge_t[e]);
  red[threadIdx.x] = m; __syncthreads();
  for (int s=128; s; s>>=1){ if ((int)threadIdx.x < s) red[threadIdx.x] = fmaxf(red[threadIdx.x], red[threadIdx.x+s]); __syncthreads(); }
  if (threadIdx.x==0) dtp[0] = red[0] / (float)NSPLITS;
}

// ---------- weight prep (bf16, [N][K] transposed layouts) ----------
__global__ void k_m12t(const float* __restrict__ W1, const float* __restrict__ W2,
                       const float* __restrict__ gw_ih, short* __restrict__ M12t) {
  int c = blockIdx.x, k = threadIdx.x;             // c<384, k<256
  const float* Wrow = (k < 128) ? (W1 + (size_t)k*128) : (W2 + (size_t)(k-128)*128);
  const float* grow = gw_ih + (size_t)c*256 + ((k < 128) ? 0 : 128);
  float s = 0.f;
  for (int j = 0; j < 128; ++j) s += Wrow[j]*grow[j];
  M12t[(size_t)c*256 + k] = f2bf(s);
}
__global__ void k_bfcopy(const float* __restrict__ src, short* __restrict__ dst) {
  size_t i = (size_t)blockIdx.x*blockDim.x + threadIdx.x;
  dst[i] = f2bf(src[i]);
}
__global__ void k_whrzt(const float* __restrict__ Whr, const float* __restrict__ Whz,
                        short* __restrict__ Whrzt) {
  int c = blockIdx.x, k = threadIdx.x;             // 256 x 128
  float v = (c < 128) ? Whr[(size_t)k*128 + c] : Whz[(size_t)k*128 + (c-128)];
  Whrzt[(size_t)c*128 + k] = f2bf(v);
}
__global__ void k_w3t(const float* __restrict__ Wxr, const float* __restrict__ Wxz,
                      const float* __restrict__ Wxh, short* __restrict__ W3t) {
  int c = blockIdx.x, k = threadIdx.x;             // 384 x 128
  float v = (c < 128) ? Wxr[(size_t)k*128 + c]
          : (c < 256) ? Wxz[(size_t)k*128 + (c-128)]
                      : Wxh[(size_t)k*128 + (c-256)];
  W3t[(size_t)c*128 + k] = f2bf(v);
}
__global__ void k_wt128(const float* __restrict__ W, short* __restrict__ Wt) {
  int c = blockIdx.x, k = threadIdx.x;             // 128 x 128
  Wt[(size_t)c*128 + k] = f2bf(W[(size_t)k*128 + c]);
}
__global__ void k_build_bias(const float* __restrict__ bxr, const float* __restrict__ bhr,
                             const float* __restrict__ bxz, const float* __restrict__ bhz,
                             const float* __restrict__ bxh, const float* __restrict__ bhh,
                             float* __restrict__ brz, float* __restrict__ bu) {
  int t = threadIdx.x;
  if (t < 128) brz[t] = bxr[t] + bhr[t];
  else if (t < 256) brz[t] = bxz[t-128] + bhz[t-128];
  else bu[t-256] = bxh[t-256] + bhh[t-256];
}

// ---------- per-group stage-C means (both directions, scatter) -> ABb bf16 ----------
__global__ __launch_bounds__(256) void k_grp_mean(const int* __restrict__ src, const int* __restrict__ dst,
                                                  const float* __restrict__ ew, const float* __restrict__ feat,
                                                  short* __restrict__ ABb) {
  __shared__ float fl[NPG*128];
  __shared__ float n1[NPG*128];
  __shared__ float n2[NPG*128];
  __shared__ int sl[EPG], tl[EPG];
  __shared__ float wl[EPG];
  __shared__ float d1[NPG], d2[NPG];
  int b = blockIdx.x, tid = threadIdx.x;
  int nb = b*NPG, eb = b*EPG;
  for (int i = tid; i < NPG*32; i += 256) {
    ((float4*)fl)[i] = ((const float4*)(feat + (size_t)nb*128))[i];
    ((float4*)n1)[i] = make_float4(0.f,0.f,0.f,0.f);
    ((float4*)n2)[i] = make_float4(0.f,0.f,0.f,0.f);
  }
  if (tid < EPG) { sl[tid] = src[eb+tid]-nb; tl[tid] = dst[eb+tid]-nb; wl[tid] = ew[eb+tid]; }
  __syncthreads();
  const int dgrp = tid >> 7, d = tid & 127;
  if (dgrp == 0) {
    for (int e = 0; e < EPG; ++e) n1[tl[e]*128+d] += fl[sl[e]*128+d]*wl[e];
  } else {
    for (int e = 0; e < EPG; ++e) n2[sl[e]*128+d] += fl[tl[e]*128+d]*wl[e];
  }
  if (tid < NPG) {
    float den = 0.f;
    for (int e = 0; e < EPG; ++e) den += (tl[e]==tid) ? wl[e] : 0.f;
    d1[tid] = (den == 0.f) ? 1.f : den;
  } else if (tid >= 128 && tid < 128+NPG) {
    int dd = tid - 128;
    float den = 0.f;
    for (int e = 0; e < EPG; ++e) den += (sl[e]==dd) ? wl[e] : 0.f;
    d2[dd] = (den == 0.f) ? 1.f : den;
  }
  __syncthreads();
  for (int n = 0; n < NPG; ++n) {
    float v = dgrp ? (n2[n*128+d]/d2[n]) : (n1[n*128+d]/d1[n]);
    ABb[(size_t)(nb+n)*256 + dgrp*128 + d] = f2bf(v);
  }
}

// ---------- GRU + l2norm (x fp32 + xb2 bf16 out) ----------
__global__ __launch_bounds__(128) void k_gru(const float* __restrict__ gi, const float* __restrict__ gh,
                                             float* __restrict__ x, short* __restrict__ xb2) {
  int n = blockIdx.x, d = threadIdx.x;
  const float* gin = gi + (size_t)n*384;
  const float* ghn = gh + (size_t)n*384;
  float ir = gin[d], iz = gin[128+d], ig = gin[256+d];
  float hr = ghn[d], hz = ghn[128+d], hg = ghn[256+d];
  float f0 = x[(size_t)n*DD + d];
  float r = sigmoidf_(ir + hr);
  float z = sigmoidf_(iz + hz);
  float g = tanhf(ig + r*hg);
  float f = (1.f - z)*g + z*f0;
  __shared__ float red2[2];
  float ss = f*f;
  for (int off=32; off; off>>=1) ss += __shfl_down(ss, off);
  if ((d & 63)==0) red2[d>>6] = ss;
  __syncthreads();
  float inv = 1.f/fmaxf(sqrtf(red2[0]+red2[1]), 1e-12f);
  float out = f*inv;
  x[(size_t)n*DD + d] = out;
  xb2[(size_t)n*DD + d] = f2bf(out);
}

// ---------- fused ODE: aggregation AS MFMA (M' tile), all dense GEMM phases ----------
// Identity used: conv(v,W) = dis * agg(dis*v) @ W = M' @ (v@W),  M' = diag(dis) M diag(dis).
// XA = x @ [Wxr|Wxz|Wxh] precomputed globally (x is split-invariant).
// Per split: T=XA_part + h@Wh* (dense), G = M'@T (dense), then sigmoid/tanh/update.
__global__ __launch_bounds__(512, 4) void k_ode_fused(
    const int* __restrict__ src, const int* __restrict__ dst,
    const float* __restrict__ edge_t, const float* __restrict__ node_t,
    const float* __restrict__ dtp,
    float* __restrict__ x, short* __restrict__ fbb,
    const short* __restrict__ XA,
    const short* __restrict__ Whrzt, const short* __restrict__ Whht,
    const float* __restrict__ brz, const float* __restrict__ bu)
{
  __shared__ __align__(16) float hl[NPG*HSTR];       // 26400 B
  __shared__ __align__(16) short rhb[NPG*RSTR];      // 13600 B
  __shared__ __align__(16) short T1t[128*TSTR];      // 18432 B (transposed T: [d][node])
  __shared__ __align__(16) short Mp[64*MSTR];        //  9216 B (M' bf16, rows=n, k=j)
  __shared__ int   rp[NPG+1];
  __shared__ short ci[2*EPG];                        // j | e<<8
  __shared__ int   cnt[NPG];
  __shared__ int   stl[EPG];
  __shared__ float etl[EPG];
  __shared__ float ntl[NPG];
  __shared__ float disl[NPG];
  __shared__ unsigned long long actm_s;
  __shared__ float red8[8];

  const int b = blockIdx.x, tid = threadIdx.x;
  const int nb = b*NPG, eb = b*EPG;
  const int wave = tid>>6, lane = tid&63, quad = lane>>4, l16 = lane&15;
  const float dtv = dtp[0];

  for (int i = tid; i < NPG*32; i += 512) {
    int n = i >> 5, dq = i & 31;
    ((float4*)(hl + n*HSTR))[dq] = ((const float4*)(x + (size_t)(nb+n)*128))[dq];
  }
  if (tid < EPG) { stl[tid] = (src[eb+tid]-nb) | ((dst[eb+tid]-nb)<<16); etl[tid] = edge_t[eb+tid]; }
  if (tid >= 64 && tid < 64+NPG) ntl[tid-64] = node_t[nb+tid-64];
  __syncthreads();

  // ---- static incidence CSR ----
  if (tid < NPG) {
    int c = 0;
    for (int e = 0; e < EPG; ++e) { int st=stl[e]; int s=st&0xffff, t=st>>16; c += (s==tid)+(t==tid); }
    cnt[tid] = c;
  }
  __syncthreads();
  if (tid == 0) { int a = 0; for (int n = 0; n < NPG; ++n) { rp[n] = a; a += cnt[n]; } rp[NPG] = a; }
  __syncthreads();
  if (tid < NPG) {
    int w = rp[tid];
    for (int e = 0; e < EPG; ++e) {
      int st = stl[e]; int s = st & 0xffff, t = st >> 16;
      if (t == tid) ci[w++] = (short)(s | (e<<8));
      if (s == tid) ci[w++] = (short)(t | (e<<8));
    }
  }
  __syncthreads();

  float zreg[4][4];

#define HW_PHASE(WT, XAOFS, USERH)                                                   \
  {                                                                                  \
    f32x4 acc[4] = {{0.f,0.f,0.f,0.f},{0.f,0.f,0.f,0.f},{0.f,0.f,0.f,0.f},{0.f,0.f,0.f,0.f}}; \
    const int coln = wave*16 + l16;                                                  \
    _Pragma("unroll")                                                                \
    for (int k0 = 0; k0 < 128; k0 += 32) {                                           \
      bfx8 af[4];                                                                    \
      _Pragma("unroll")                                                              \
      for (int m = 0; m < 4; ++m) {                                                  \
        int arow = m*16 + l16; if (arow > NPG-1) arow = NPG-1;                       \
        if (USERH) {                                                                 \
          af[m] = *(const bfx8*)&rhb[arow*RSTR + k0 + quad*8];                       \
        } else {                                                                     \
          const float* hp = &hl[arow*HSTR + k0 + quad*8];                            \
          float4 f0 = *(const float4*)hp;                                            \
          float4 f1 = *(const float4*)(hp+4);                                        \
          af[m] = pack8(f0, f1);                                                     \
        }                                                                            \
      }                                                                              \
      bfx8 bfr = *(const bfx8*)&(WT)[(size_t)coln*128 + k0 + quad*8];                \
      _Pragma("unroll")                                                              \
      for (int m = 0; m < 4; ++m)                                                    \
        acc[m] = __builtin_amdgcn_mfma_f32_16x16x32_bf16(af[m], bfr, acc[m], 0, 0, 0); \
    }                                                                                \
    _Pragma("unroll")                                                                \
    for (int m = 0; m < 4; ++m)                                                      \
      _Pragma("unroll")                                                              \
      for (int r = 0; r < 4; ++r) {                                                  \
        int row = m*16 + quad*4 + r;                                                 \
        int crow = (row > NPG-1) ? (NPG-1) : row;                                    \
        float v = acc[m][r] + bf2f(XA[(size_t)(nb+crow)*384 + (XAOFS) + coln]);      \
        T1t[coln*TSTR + row] = f2bf(v);                                              \
      }                                                                              \
  }

#define AGG_PHASE(WHICH)                                                             \
  {                                                                                  \
    f32x4 acc[4] = {{0.f,0.f,0.f,0.f},{0.f,0.f,0.f,0.f},{0.f,0.f,0.f,0.f},{0.f,0.f,0.f,0.f}}; \
    const int cold = wave*16 + l16;                                                  \
    _Pragma("unroll")                                                                \
    for (int k0 = 0; k0 < 64; k0 += 32) {                                            \
      bfx8 af[4];                                                                    \
      _Pragma("unroll")                                                              \
      for (int m = 0; m < 4; ++m) af[m] = *(const bfx8*)&Mp[(m*16+l16)*MSTR + k0 + quad*8]; \
      bfx8 bfr = *(const bfx8*)&T1t[cold*TSTR + k0 + quad*8];                        \
      _Pragma("unroll")                                                              \
      for (int m = 0; m < 4; ++m)                                                    \
        acc[m] = __builtin_amdgcn_mfma_f32_16x16x32_bf16(af[m], bfr, acc[m], 0, 0, 0); \
    }                                                                                \
    if ((WHICH) == 0) {                                                              \
      float bb = brz[cold];                                                          \
      _Pragma("unroll")                                                              \
      for (int m = 0; m < 4; ++m)                                                    \
        _Pragma("unroll")                                                            \
        for (int r = 0; r < 4; ++r) {                                                \
          int row = m*16 + quad*4 + r;                                               \
          if (row < NPG) {                                                           \
            float s = sigmoidf_(acc[m][r] + bb);                                     \
            rhb[row*RSTR + cold] = f2bf(s * hl[row*HSTR + cold]);                    \
          }                                                                          \
        }                                                                            \
    } else if ((WHICH) == 1) {                                                       \
      float bb = brz[128 + cold];                                                    \
      _Pragma("unroll")                                                              \
      for (int m = 0; m < 4; ++m)                                                    \
        _Pragma("unroll")                                                            \
        for (int r = 0; r < 4; ++r)                                                  \
          zreg[m][r] = sigmoidf_(acc[m][r] + bb);                                    \
    } else {                                                                         \
      float bb = bu[cold];                                                           \
      _Pragma("unroll")                                                              \
      for (int m = 0; m < 4; ++m)                                                    \
        _Pragma("unroll")                                                            \
        for (int r = 0; r < 4; ++r) {                                                \
          int row = m*16 + quad*4 + r;                                               \
          if (row < NPG && ntl[row] >= t) {                                          \
            float hv = hl[row*HSTR + cold];                                          \
            float uu = tanhf(acc[m][r] + bb);                                        \
            hl[row*HSTR + cold] = hv + dtv*(1.f - zreg[m][r])*(uu - hv);             \
          }                                                                          \
        }                                                                            \
    }                                                                                \
  }

  for (int ks = 0; ks < NSPLITS; ++ks) {
    const float t = (float)ks * dtv;
    // --- mask (wave 0) + zero M' (all) ---
    if (wave == 0) {
      bool p = false;
      if (lane < EPG) {
        int st = stl[lane]; int s = st & 0xffff, tt = st >> 16;
        p = (etl[lane] <= t) && (ntl[s] >= t) && (ntl[tt] >= t) && (s != tt);
      }
      unsigned long long m = __ballot(p);
      if (lane == 0) actm_s = m;
    }
    for (int i = tid; i < 64*MSTR/2; i += 512) ((int*)Mp)[i] = 0;
    __syncthreads();
    const unsigned long long actm = actm_s;
    // --- deg -> dis ---
    if (tid < NPG) {
      float deg = 0.f;
      for (int idx = rp[tid]; idx < rp[tid+1]; ++idx)
        deg += (float)((actm >> (((int)ci[idx]) >> 8)) & 1ULL);
      disl[tid] = rsqrtf(fmaxf(deg, 1.f));
    }
    __syncthreads();
    // --- build M' (row-owned, serial per thread) ---
    if (tid < NPG) {
      float dn = disl[tid];
      for (int idx = rp[tid]; idx < rp[tid+1]; ++idx) {
        int v = ci[idx]; int j = v & 255, e = v >> 8;
        if ((actm >> e) & 1ULL)
          Mp[tid*MSTR + j] = f2bf(bf2f(Mp[tid*MSTR + j]) + dn*disl[j]);
      }
    }
    __syncthreads();

    HW_PHASE(Whrzt, 0, false);            __syncthreads();   // T = XA_r + h@Whr
    AGG_PHASE(0);                         __syncthreads();   // r -> rh
    HW_PHASE(Whrzt + 128*128, 128, false);__syncthreads();   // T = XA_z + h@Whz
    AGG_PHASE(1);                         __syncthreads();   // z -> regs
    HW_PHASE(Whht, 256, true);            __syncthreads();   // T = XA_h + rh@Whh
    AGG_PHASE(2);                         __syncthreads();   // u -> h update
  }
#undef HW_PHASE
#undef AGG_PHASE

  // --- final l2norm of h -> x (fp32) + fbb (bf16), 4 rows/iter ---
  for (int rr0 = 0; rr0 < NPG; rr0 += 4) {
    const int r = rr0 + (tid>>7);
    const int d = tid & 127;
    float v = (r < NPG) ? hl[r*HSTR + d] : 0.f;
    float ss = v*v;
    for (int off=32; off; off>>=1) ss += __shfl_down(ss, off);
    if (lane == 0) red8[wave] = ss;
    __syncthreads();
    int g = tid>>7;
    float inv = 1.f/fmaxf(sqrtf(red8[2*g]+red8[2*g+1]), 1e-12f);
    if (r < NPG) {
      float f = v*inv;
      x[(size_t)(nb+r)*128 + d] = f;
      fbb[(size_t)(nb+r)*128 + d] = f2bf(f);
    }
    __syncthreads();
  }
}

// ---------- bf16 MFMA GEMM: 64x64 block tile, 4 waves, 16x16x32 ----------
// modes: 0: C=A@B+bias (fp32); 6: C=A@B bf16 store;
// 4: logits LSE partials (grid 8*NCB linear, XCD-swizzled); 5: out = acc - lse[row]
__global__ __launch_bounds__(256) void gemm_mfma(
    const short* __restrict__ A, int lda,
    const short* __restrict__ Bt, int ldbt,
    const float* __restrict__ bias,
    float* __restrict__ C, int ldc,
    int K, int mode,
    float* __restrict__ outp, float* __restrict__ pmax, float* __restrict__ psum)
{
  __shared__ short As[64*40];
  __shared__ short Bs[64*40];
  const int tid = threadIdx.x;
  const int wave = tid >> 6, lane = tid & 63;
  const int wr = wave >> 1, wc = wave & 1;
  const int quad = lane >> 4, l16 = lane & 15;
  int rb, cb;
  if (mode == 4 || mode == 5) {
    int t = (blockIdx.x & 7)*1563 + (blockIdx.x >> 3);   // 12504 = 8*1563
    rb = t & 7; cb = t >> 3;
  } else { rb = blockIdx.y; cb = blockIdx.x; }
  const int row0 = rb*64, col0 = cb*64;
  f32x4 acc[2][2] = {{{0.f,0.f,0.f,0.f},{0.f,0.f,0.f,0.f}},{{0.f,0.f,0.f,0.f},{0.f,0.f,0.f,0.f}}};
  const int sm = tid >> 2, skq = tid & 3;
  const short* Ap = A + (size_t)(row0+sm)*lda + skq*8;
  const short* Bp = Bt + (size_t)(col0+sm)*ldbt + skq*8;
  for (int k0 = 0; k0 < K; k0 += 32) {
    *(bfx8*)&As[sm*40 + skq*8] = *(const bfx8*)(Ap + k0);
    *(bfx8*)&Bs[sm*40 + skq*8] = *(const bfx8*)(Bp + k0);
    __syncthreads();
    bfx8 a0 = *(bfx8*)&As[(wr*32 + l16)*40 + quad*8];
    bfx8 a1 = *(bfx8*)&As[(wr*32 + 16 + l16)*40 + quad*8];
    bfx8 b0 = *(bfx8*)&Bs[(wc*32 + l16)*40 + quad*8];
    bfx8 b1 = *(bfx8*)&Bs[(wc*32 + 16 + l16)*40 + quad*8];
    acc[0][0] = __builtin_amdgcn_mfma_f32_16x16x32_bf16(a0, b0, acc[0][0], 0, 0, 0);
    acc[0][1] = __builtin_amdgcn_mfma_f32_16x16x32_bf16(a0, b1, acc[0][1], 0, 0, 0);
    acc[1][0] = __builtin_amdgcn_mfma_f32_16x16x32_bf16(a1, b0, acc[1][0], 0, 0, 0);
    acc[1][1] = __builtin_amdgcn_mfma_f32_16x16x32_bf16(a1, b1, acc[1][1], 0, 0, 0);
    __syncthreads();
  }

  if (mode == 0) {
#pragma unroll
    for (int i = 0; i < 2; ++i)
#pragma unroll
      for (int j = 0; j < 2; ++j) {
        int gc = col0 + wc*32 + j*16 + l16;
        float bb = bias ? bias[gc] : 0.f;
#pragma unroll
        for (int r = 0; r < 4; ++r) {
          int gr = row0 + wr*32 + i*16 + quad*4 + r;
          C[(size_t)gr*ldc + gc] = acc[i][j][r] + bb;
        }
      }
  } else if (mode == 6) {
    short* Cb = (short*)C;
#pragma unroll
    for (int i = 0; i < 2; ++i)
#pragma unroll
      for (int j = 0; j < 2; ++j) {
        int gc = col0 + wc*32 + j*16 + l16;
#pragma unroll
        for (int r = 0; r < 4; ++r) {
          int gr = row0 + wr*32 + i*16 + quad*4 + r;
          Cb[(size_t)gr*ldc + gc] = f2bf(acc[i][j][r]);
        }
      }
  } else if (mode == 4) { // LSE partials: max-reduce first, then sum(exp)
    __shared__ float pm[64][2], ps[64][2];
    int c0 = col0 + wc*32 + l16;
    int c1 = c0 + 16;
#pragma unroll
    for (int i = 0; i < 2; ++i) {
#pragma unroll
      for (int r = 0; r < 4; ++r) {
        int rloc = wr*32 + i*16 + quad*4 + r;
        float v0 = (c0 < VV) ? acc[i][0][r] : -1e30f;
        float v1 = (c1 < VV) ? acc[i][1][r] : -1e30f;
        float m = fmaxf(v0, v1);
#pragma unroll
        for (int off = 1; off < 16; off <<= 1) m = fmaxf(m, __shfl_xor(m, off));
        float s = expf(v0 - m) + expf(v1 - m);
#pragma unroll
        for (int off = 1; off < 16; off <<= 1) s += __shfl_xor(s, off);
        if (l16 == 0) { pm[rloc][wc] = m; ps[rloc][wc] = s; }
      }
    }
    __syncthreads();
    if (tid < 64) {
      float m0 = pm[tid][0], m1 = pm[tid][1];
      float s0 = ps[tid][0], s1 = ps[tid][1];
      float M = fmaxf(m0, m1);
      float S = s0*expf(m0 - M) + s1*expf(m1 - M);
      pmax[(size_t)(row0 + tid)*NCB + cb] = M;
      psum[(size_t)(row0 + tid)*NCB + cb] = S;
    }
  } else { // mode 5: out = acc - lse[row]   (bias = lse)
#pragma unroll
    for (int i = 0; i < 2; ++i) {
#pragma unroll
      for (int r = 0; r < 4; ++r) {
        int gr = row0 + wr*32 + i*16 + quad*4 + r;
        float l = bias[gr];
#pragma unroll
        for (int j = 0; j < 2; ++j) {
          int gc = col0 + wc*32 + j*16 + l16;
          if (gc < VV) outp[(size_t)gr*VV + gc] = acc[i][j][r] - l;
        }
      }
    }
  }
}

// ---------- attention readout + W_sr + l2norm -> srvb bf16 (pre-scaled) ----------
__global__ __launch_bounds__(128) void k_attn(const float* __restrict__ fb, const float* __restrict__ U,
                                              const float* __restrict__ lv, const float* __restrict__ We,
                                              const float* __restrict__ W_sr, short* __restrict__ srvb) {
  int b = blockIdx.x, d = threadIdx.x;
  __shared__ float sc[NPG];
  __shared__ float lastv[DD], srg[DD];
  __shared__ float red2[2];
  const float* Ub  = U  + (size_t)b*NPG*DD;
  const float* lvb = lv + (size_t)b*DD;
  if (d < 64) {
    for (int i=0;i<NPG;++i) {
      float e = We[d]   * sigmoidf_(Ub[i*DD + d]      + lvb[d]) +
                We[d+64]* sigmoidf_(Ub[i*DD + 64 + d] + lvb[d+64]);
      for (int off=32; off; off>>=1) e += __shfl_down(e, off);
      if (d==0) sc[i] = e;
    }
  }
  __syncthreads();
  if (d < 64) {
    float v = (d < NPG) ? sc[d] : -1e30f;
    float m = v;
    for (int off=1; off<64; off<<=1) m = fmaxf(m, __shfl_xor(m, off));
    float ex = (d < NPG) ? expf(v - m) : 0.f;
    float s = ex;
    for (int off=1; off<64; off<<=1) s += __shfl_xor(s, off);
    if (d < NPG) sc[d] = ex/s;
  }
  __syncthreads();
  const float* fbb = fb + (size_t)b*NPG*DD;
  float lastd = fbb[(NPG-1)*DD + d];
  float sg = 0.f;
  for (int i=0;i<NPG;++i) sg += fbb[i*DD + d]*sc[i];
  lastv[d] = lastd; srg[d] = sg;
  __syncthreads();
  float acc = 0.f;
  for (int k=0;k<DD;++k) acc += lastv[k]*W_sr[k*DD + d];
  for (int k=0;k<DD;++k) acc += srg[k]*W_sr[(DD+k)*DD + d];
  float ss = acc*acc;
  for (int off=32; off; off>>=1) ss += __shfl_down(ss, off);
  if ((d & 63)==0) red2[d>>6] = ss;
  __syncthreads();
  float inv = 1.f/fmaxf(sqrtf(red2[0]+red2[1]), 1e-12f);
  srvb[(size_t)b*DD + d] = f2bf(FSCALE*acc*inv);
}

__global__ __launch_bounds__(256) void k_lse(const float* __restrict__ pmax, const float* __restrict__ psum,
                                             float* __restrict__ lse) {
  int r = blockIdx.x, tid = threadIdx.x;
  float m = -1e30f, s = 0.f;
  for (int cb = tid; cb < NCB; cb += 256) {
    float m2 = pmax[(size_t)r*NCB + cb], s2 = psum[(size_t)r*NCB + cb];
    float M = fmaxf(m, m2);
    s = s*expf(m - M) + s2*expf(m2 - M);
    m = M;
  }
  __shared__ float ms[256], ssh[256];
  ms[tid] = m; ssh[tid] = s; __syncthreads();
  for (int st=128; st; st>>=1) {
    if (tid < st) {
      float m2 = ms[tid+st], s2 = ssh[tid+st];
      float M = fmaxf(ms[tid], m2);
      ssh[tid] = ssh[tid]*expf(ms[tid]-M) + s2*expf(m2-M);
      ms[tid] = M;
    }
    __syncthreads();
  }
  if (tid==0) lse[r] = ms[0] + logf(ssh[0]);
}

extern "C" void kernel_launch(void* const* d_in, const int* in_sizes, int n_in,
                              void* d_out, int out_size, void* d_ws, size_t ws_size,
                              hipStream_t stream) {
  (void)in_sizes; (void)n_in; (void)out_size; (void)ws_size;
  const int*   iid    = (const int*)  d_in[0];
  const int*   src    = (const int*)  d_in[1];
  const int*   dst    = (const int*)  d_in[2];
  const float* edge_w = (const float*)d_in[3];
  const float* edge_t = (const float*)d_in[4];
  const float* node_t = (const float*)d_in[5];
  const float* emb    = (const float*)d_in[6];
  const float* W1     = (const float*)d_in[7];
  const float* W2     = (const float*)d_in[8];
  const float* gw_ih  = (const float*)d_in[9];
  const float* gw_hh  = (const float*)d_in[10];
  const float* gb_ih  = (const float*)d_in[11];
  const float* gb_hh  = (const float*)d_in[12];
  const float* Wxr = (const float*)d_in[13]; const float* bxr = (const float*)d_in[14];
  const float* Wxz = (const float*)d_in[15]; const float* bxz = (const float*)d_in[16];
  const float* Wxh = (const float*)d_in[17]; const float* bxh = (const float*)d_in[18];
  const float* Whr = (const float*)d_in[19]; const float* bhr = (const float*)d_in[20];
  const float* Whz = (const float*)d_in[21]; const float* bhz = (const float*)d_in[22];
  const float* Whh = (const float*)d_in[23]; const float* bhh = (const float*)d_in[24];
  const float* Wu  = (const float*)d_in[25];
  const float* Wv  = (const float*)d_in[26]; const float* bv  = (const float*)d_in[27];
  const float* We  = (const float*)d_in[28];
  const float* W_sr= (const float*)d_in[29];

  float* ws  = (float*)d_ws;
  float* out = (float*)d_out;

  // ---- workspace layout (float units; shorts live in float-sized slots) ----
  short* embn  = (short*)ws;                        // VPAD*128 sh = 6,402,048 fl
  float* pmax  = ws + 6402048;                      // 800,256
  float* psum  = pmax + 800256;                     // 800,256   -> 8,002,560
  short* M12t  = (short*)(ws + 8002560);            // 384*256 sh = 49,152 fl
  short* gwhhb = (short*)(ws + 8051712);            // 384*128 sh = 24,576 fl
  short* Whrzt = (short*)(ws + 8076288);            // 256*128 sh = 16,384 fl
  short* Whht  = (short*)(ws + 8092672);            // 128*128 sh =  8,192 fl
  short* W3t   = (short*)(ws + 8100864);            // 384*128 sh = 24,576 fl
  short* Wut   = (short*)(ws + 8125440);            //  8,192 fl
  short* Wvt   = (short*)(ws + 8133632);            //  8,192 fl
  float* brz   = ws + 8141824;                      // 256
  float* bu    = brz + 256;                         // 128
  float* lv    = bu + 128;                          // 65,536
  float* dtp   = lv + 65536;                        // 4
  float* lse   = dtp + 4;                           // 512
  short* srvb  = (short*)(lse + 512);               // 512*128 sh = 32,768 sh

  // ---- d_out as scratch until the logits pass (51.2M floats) ----
  short* ABb = (short*)out;                          // 25600*256 sh (3.28M fl)
  float* x   = out + (size_t) 4*1024*1024;           // 3.28M
  short* XA  = (short*)(out + (size_t) 8*1024*1024); // 25600*384 sh (4.92M fl)
  float* gi  = out + (size_t)20*1024*1024;           // 9.83M
  float* gh  = out + (size_t)30*1024*1024;           // 9.83M
  float* U   = out + (size_t)20*1024*1024;           // reuse gi after GRU
  short* xb  = (short*)(out + (size_t)40*1024*1024); // 25600*128 sh (1.64M fl)
  short* xb2 = (short*)(out + (size_t)44*1024*1024); // 1.64M fl
  short* fbb = (short*)(out + (size_t)46*1024*1024); // 1.64M fl

  // ---- prep ----
  k_embn<<<VPAD/4, 256, 0, stream>>>(emb, embn);
  k_gather<<<NN, 128, 0, stream>>>(iid, emb, x, xb);
  k_dt<<<1, 256, 0, stream>>>(edge_t, dtp);
  k_m12t<<<384, 256, 0, stream>>>(W1, W2, gw_ih, M12t);
  k_bfcopy<<<384, 128, 0, stream>>>(gw_hh, gwhhb);
  k_whrzt<<<256, 128, 0, stream>>>(Whr, Whz, Whrzt);
  k_wt128<<<128, 128, 0, stream>>>(Whh, Whht);
  k_w3t<<<384, 128, 0, stream>>>(Wxr, Wxz, Wxh, W3t);
  k_wt128<<<128, 128, 0, stream>>>(Wu, Wut);
  k_wt128<<<128, 128, 0, stream>>>(Wv, Wvt);
  k_build_bias<<<1, 384, 0, stream>>>(bxr, bhr, bxz, bhz, bxh, bhh, brz, bu);

  // ---- stage C ----
  k_grp_mean<<<BB, 256, 0, stream>>>(src, dst, edge_w, x, ABb);

  // ---- GRU ----
  gemm_mfma<<<dim3(6,400), 256, 0, stream>>>(ABb, 256, M12t, 256, gb_ih, gi, 384, 256, 0,
      nullptr, nullptr, nullptr);
  gemm_mfma<<<dim3(6,400), 256, 0, stream>>>(xb, 128, gwhhb, 128, gb_hh, gh, 384, 128, 0,
      nullptr, nullptr, nullptr);
  k_gru<<<NN, 128, 0, stream>>>(gi, gh, x, xb2);

  // ---- XA = x @ [Wxr|Wxz|Wxh] (bf16 out), split-invariant ----
  gemm_mfma<<<dim3(6,400), 256, 0, stream>>>(xb2, 128, W3t, 128, nullptr, (float*)XA, 384, 128, 6,
      nullptr, nullptr, nullptr);

  // ---- ODE (aggregation-as-MFMA, all dense phases in LDS) ----
  k_ode_fused<<<BB, 512, 0, stream>>>(src, dst, edge_t, node_t, dtp, x, fbb, XA, Whrzt, Whht, brz, bu);

  // ---- attention ----
  gemm_mfma<<<dim3(2,400), 256, 0, stream>>>(fbb, 128, Wut, 128, nullptr, U, 128, 128, 0,
      nullptr, nullptr, nullptr);
  gemm_mfma<<<dim3(2,8), 256, 0, stream>>>(fbb + (size_t)(NPG-1)*DD, NPG*DD, Wvt, 128, bv, lv, 128, 128, 0,
      nullptr, nullptr, nullptr);
  k_attn<<<BB, 128, 0, stream>>>(x, U, lv, We, W_sr, srvb);

  // ---- logits: pass 1 (LSE partials) -> lse -> pass 2 (store acc - lse) ----
  gemm_mfma<<<dim3(8*NCB), 256, 0, stream>>>(srvb, 128, embn, 128, nullptr, nullptr, 0, 128, 4,
      nullptr, pmax, psum);
  k_lse<<<BB, 256, 0, stream>>>(pmax, psum, lse);
  gemm_mfma<<<dim3(8*NCB), 256, 0, stream>>>(srvb, 128, embn, 128, lse, nullptr, 0, 128, 5,
      out, nullptr, nullptr);
}

// Round 5
// 655.310 us; speedup vs baseline: 1.3033x; 1.0833x over previous
//
#include <hip/hip_runtime.h>

#define BB 512
#define NPG 50
#define EPG 60
#define DD 128
#define VV 100000
#define VPAD 100032
#define NSPLITS 4
#define FSCALE 12.0f
#define NN (BB*NPG)        // 25600
#define EE (BB*EPG)        // 30720
#define NCB (VPAD/64)      // 1563
#define HSTR 132           // hl fp32 row stride
#define RSTR 136           // rhb/U bf16 row stride
#define TSTR 72            // T1t bf16 row stride
#define MSTR 72            // Mp bf16 row stride
#define FTSTR 72           // featT bf16 row stride (k_grp_mean)

typedef __attribute__((ext_vector_type(8))) short bfx8;
typedef __attribute__((ext_vector_type(4))) float f32x4;

__device__ __forceinline__ float sigmoidf_(float x){ return 1.f/(1.f+expf(-x)); }
__device__ __forceinline__ short f2bf(float f){
  union { float f; unsigned u; } v; v.f = f;
  unsigned r = v.u + 0x7FFF + ((v.u >> 16) & 1);
  return (short)(r >> 16);
}
__device__ __forceinline__ float bf2f(short s){
  union { unsigned u; float f; } v; v.u = ((unsigned)(unsigned short)s) << 16;
  return v.f;
}
__device__ __forceinline__ unsigned cvtpk_(float lo, float hi){
  unsigned r; asm("v_cvt_pk_bf16_f32 %0, %1, %2" : "=v"(r) : "v"(lo), "v"(hi)); return r;
}
__device__ __forceinline__ bfx8 pack8(float4 a, float4 b){
  union { bfx8 v; unsigned u[4]; } w;
  w.u[0] = cvtpk_(a.x, a.y); w.u[1] = cvtpk_(a.z, a.w);
  w.u[2] = cvtpk_(b.x, b.y); w.u[3] = cvtpk_(b.z, b.w);
  return w.v;
}

// ---------- embn = l2norm(emb) in bf16, padded to VPAD rows ----------
__global__ __launch_bounds__(256) void k_embn(const float* __restrict__ emb, short* __restrict__ embn) {
  int row = blockIdx.x*4 + (threadIdx.x >> 6);
  int lane = threadIdx.x & 63;
  if (row >= VPAD) return;
  if (row >= VV) { embn[(size_t)row*DD+lane]=0; embn[(size_t)row*DD+64+lane]=0; return; }
  const float* r = emb + (size_t)row*DD;
  float a = r[lane], b = r[lane+64];
  float s = a*a + b*b;
  for (int off=32; off; off>>=1) s += __shfl_down(s, off);
  s = __shfl(s, 0);
  float inv = 1.0f/fmaxf(sqrtf(s), 1e-12f);
  embn[(size_t)row*DD+lane]    = f2bf(a*inv);
  embn[(size_t)row*DD+64+lane] = f2bf(b*inv);
}

// ---------- feat = l2norm(emb[iid]) -> x fp32 + xb bf16 ----------
__global__ __launch_bounds__(128) void k_gather(const int* __restrict__ iid, const float* __restrict__ emb,
                                                float* __restrict__ x, short* __restrict__ xb) {
  int n = blockIdx.x, d = threadIdx.x;
  int v = iid[n];
  float e = emb[(size_t)v*DD + d];
  __shared__ float red2[2];
  float ss = e*e;
  for (int off=32; off; off>>=1) ss += __shfl_down(ss, off);
  if ((d & 63)==0) red2[d>>6] = ss;
  __syncthreads();
  float inv = 1.f/fmaxf(sqrtf(red2[0]+red2[1]), 1e-12f);
  float f = e*inv;
  x[(size_t)n*DD + d] = f;
  xb[(size_t)n*DD + d] = f2bf(f);
}

// ---------- merged weight prep + biases + dt (grid-range dispatch, 256 thr) ----------
__global__ __launch_bounds__(256) void k_prep(
    const float* __restrict__ W1, const float* __restrict__ W2, const float* __restrict__ gw_ih,
    const float* __restrict__ gw_hh,
    const float* __restrict__ Whr, const float* __restrict__ Whz, const float* __restrict__ Whh,
    const float* __restrict__ Wxr, const float* __restrict__ Wxz, const float* __restrict__ Wxh,
    const float* __restrict__ Wu, const float* __restrict__ Wv,
    const float* __restrict__ bxr, const float* __restrict__ bhr,
    const float* __restrict__ bxz, const float* __restrict__ bhz,
    const float* __restrict__ bxh, const float* __restrict__ bhh,
    const float* __restrict__ edge_t,
    short* __restrict__ M12t, short* __restrict__ gwhhb,
    short* __restrict__ Whrzt, short* __restrict__ Whht, short* __restrict__ W3t,
    short* __restrict__ Wut, short* __restrict__ Wvt,
    float* __restrict__ brz, float* __restrict__ bu, float* __restrict__ dtp)
{
  const int blk = blockIdx.x, tid = threadIdx.x;
  if (blk < 384) {                 // M12t = [W1|W2] fused with gw_ih
    int c = blk, k = tid;
    const float* Wrow = (k < 128) ? (W1 + (size_t)k*128) : (W2 + (size_t)(k-128)*128);
    const float* grow = gw_ih + (size_t)c*256 + ((k < 128) ? 0 : 128);
    float s = 0.f;
    for (int j = 0; j < 128; ++j) s += Wrow[j]*grow[j];
    M12t[(size_t)c*256 + k] = f2bf(s);
  } else if (blk < 576) {          // gw_hh -> bf16 copy (49152)
    int i = (blk-384)*256 + tid;
    gwhhb[i] = f2bf(gw_hh[i]);
  } else if (blk < 704) {          // Whrzt [256][128] transposed
    int c = ((blk-576)<<1) | (tid>>7), k = tid & 127;
    float v = (c < 128) ? Whr[(size_t)k*128+c] : Whz[(size_t)k*128+(c-128)];
    Whrzt[(size_t)c*128 + k] = f2bf(v);
  } else if (blk < 768) {          // Whht [128][128] transposed
    int c = ((blk-704)<<1) | (tid>>7), k = tid & 127;
    Whht[(size_t)c*128 + k] = f2bf(Whh[(size_t)k*128 + c]);
  } else if (blk < 960) {          // W3t [384][128] transposed
    int c = ((blk-768)<<1) | (tid>>7), k = tid & 127;
    float v = (c < 128) ? Wxr[(size_t)k*128 + c]
            : (c < 256) ? Wxz[(size_t)k*128 + (c-128)]
                        : Wxh[(size_t)k*128 + (c-256)];
    W3t[(size_t)c*128 + k] = f2bf(v);
  } else if (blk < 1024) {         // Wut
    int c = ((blk-960)<<1) | (tid>>7), k = tid & 127;
    Wut[(size_t)c*128 + k] = f2bf(Wu[(size_t)k*128 + c]);
  } else if (blk < 1088) {         // Wvt
    int c = ((blk-1024)<<1) | (tid>>7), k = tid & 127;
    Wvt[(size_t)c*128 + k] = f2bf(Wv[(size_t)k*128 + c]);
  } else if (blk == 1088) {        // biases
    for (int t = tid; t < 384; t += 256) {
      if (t < 128) brz[t] = bxr[t] + bhr[t];
      else if (t < 256) brz[t] = bxz[t-128] + bhz[t-128];
      else bu[t-256] = bxh[t-256] + bhh[t-256];
    }
  } else {                         // dt = max(edge_t)/NSPLITS
    __shared__ float red[256];
    float m = -1e30f;
    for (int e = tid; e < EE; e += 256) m = fmaxf(m, edge_t[e]);
    red[tid] = m; __syncthreads();
    for (int s=128; s; s>>=1){ if (tid < s) red[tid] = fmaxf(red[tid], red[tid+s]); __syncthreads(); }
    if (tid==0) dtp[0] = red[0] / (float)NSPLITS;
  }
}

// ---------- stage-C means as MFMA: ABb = [Mw1@feat | Mw2@feat] ----------
__global__ __launch_bounds__(512) void k_grp_mean(const int* __restrict__ src, const int* __restrict__ dst,
                                                  const float* __restrict__ ew, const float* __restrict__ feat,
                                                  short* __restrict__ ABb) {
  __shared__ __align__(16) short featT[128*FTSTR];  // 18432 B, [d][node]
  __shared__ __align__(16) float Mwf[2][64*64];     // 32768 B
  __shared__ __align__(16) short Mw[2][64*MSTR];    // 18432 B
  __shared__ float den[2][64];
  __shared__ int stl[EPG];
  __shared__ float wl[EPG];
  const int b = blockIdx.x, tid = threadIdx.x;
  const int nb = b*NPG, eb = b*EPG;
  const int wave = tid>>6, lane = tid&63, quad = lane>>4, l16 = lane&15;
  if (tid < EPG) { stl[tid] = (src[eb+tid]-nb) | ((dst[eb+tid]-nb)<<16); wl[tid] = ew[eb+tid]; }
  for (int i = tid; i < 64*32; i += 512) {
    int n = i >> 5, fq = i & 31;
    float4 v = (n < NPG) ? ((const float4*)(feat + (size_t)(nb+n)*128))[fq] : make_float4(0.f,0.f,0.f,0.f);
    featT[(fq*4+0)*FTSTR + n] = f2bf(v.x);
    featT[(fq*4+1)*FTSTR + n] = f2bf(v.y);
    featT[(fq*4+2)*FTSTR + n] = f2bf(v.z);
    featT[(fq*4+3)*FTSTR + n] = f2bf(v.w);
  }
  for (int i = tid; i < 2*64*64; i += 512) ((float*)Mwf)[i] = 0.f;
  if (tid < 128) den[tid>>6][tid&63] = 1.f;
  __syncthreads();
  if (tid < NPG) {
    float dA = 0.f;
    for (int e = 0; e < EPG; ++e) {
      int st = stl[e]; int s = st & 0xffff, t = st >> 16;
      if (t == tid) { Mwf[0][tid*64 + s] += wl[e]; dA += wl[e]; }
    }
    den[0][tid] = (dA == 0.f) ? 1.f : dA;
  } else if (tid >= 64 && tid < 64+NPG) {
    int n = tid - 64; float dB = 0.f;
    for (int e = 0; e < EPG; ++e) {
      int st = stl[e]; int s = st & 0xffff, t = st >> 16;
      if (s == n) { Mwf[1][n*64 + t] += wl[e]; dB += wl[e]; }
    }
    den[1][n] = (dB == 0.f) ? 1.f : dB;
  }
  __syncthreads();
  for (int i = tid; i < 2*64*64; i += 512) {
    int q = i >> 12, rr = (i >> 6) & 63, j = i & 63;
    Mw[q][rr*MSTR + j] = f2bf(Mwf[q][rr*64 + j] / den[q][rr]);
  }
  __syncthreads();
#pragma unroll
  for (int q = 0; q < 2; ++q) {
    f32x4 acc[4] = {{0.f,0.f,0.f,0.f},{0.f,0.f,0.f,0.f},{0.f,0.f,0.f,0.f},{0.f,0.f,0.f,0.f}};
    const int coln = wave*16 + l16;
#pragma unroll
    for (int k0 = 0; k0 < 64; k0 += 32) {
      bfx8 af[4];
#pragma unroll
      for (int m = 0; m < 4; ++m) af[m] = *(const bfx8*)&Mw[q][(m*16+l16)*MSTR + k0 + quad*8];
      bfx8 bfr = *(const bfx8*)&featT[coln*FTSTR + k0 + quad*8];
#pragma unroll
      for (int m = 0; m < 4; ++m)
        acc[m] = __builtin_amdgcn_mfma_f32_16x16x32_bf16(af[m], bfr, acc[m], 0, 0, 0);
    }
#pragma unroll
    for (int m = 0; m < 4; ++m)
#pragma unroll
      for (int r = 0; r < 4; ++r) {
        int row = m*16 + quad*4 + r;
        if (row < NPG) ABb[(size_t)(nb+row)*256 + q*128 + coln] = f2bf(acc[m][r]);
      }
  }
}

// ---------- GRU + l2norm (x fp32 + xb2 bf16 out) ----------
__global__ __launch_bounds__(128) void k_gru(const float* __restrict__ gi, const float* __restrict__ gh,
                                             float* __restrict__ x, short* __restrict__ xb2) {
  int n = blockIdx.x, d = threadIdx.x;
  const float* gin = gi + (size_t)n*384;
  const float* ghn = gh + (size_t)n*384;
  float ir = gin[d], iz = gin[128+d], ig = gin[256+d];
  float hr = ghn[d], hz = ghn[128+d], hg = ghn[256+d];
  float f0 = x[(size_t)n*DD + d];
  float r = sigmoidf_(ir + hr);
  float z = sigmoidf_(iz + hz);
  float g = tanhf(ig + r*hg);
  float f = (1.f - z)*g + z*f0;
  __shared__ float red2[2];
  float ss = f*f;
  for (int off=32; off; off>>=1) ss += __shfl_down(ss, off);
  if ((d & 63)==0) red2[d>>6] = ss;
  __syncthreads();
  float inv = 1.f/fmaxf(sqrtf(red2[0]+red2[1]), 1e-12f);
  float out = f*inv;
  x[(size_t)n*DD + d] = out;
  xb2[(size_t)n*DD + d] = f2bf(out);
}

// ---------- fused ODE + attention readout, all per-group in LDS ----------
// conv(v,W) = M' @ (v@W), M' = diag(dis) M diag(dis). XA precomputed.
// Epilogue: l2norm(h) in-place, U=fb@Wu, lv, softmax scores, sr_g, W_sr, l2norm -> srvb.
__global__ __launch_bounds__(512, 4) void k_ode_fused(
    const int* __restrict__ src, const int* __restrict__ dst,
    const float* __restrict__ edge_t, const float* __restrict__ node_t,
    const float* __restrict__ dtp,
    const float* __restrict__ x,
    const short* __restrict__ XA,
    const short* __restrict__ Whrzt, const short* __restrict__ Whht,
    const float* __restrict__ brz, const float* __restrict__ bu,
    const short* __restrict__ Wut, const short* __restrict__ Wvt,
    const float* __restrict__ bv, const float* __restrict__ We_,
    const float* __restrict__ W_sr, short* __restrict__ srvb)
{
  __shared__ __align__(16) float hl[NPG*HSTR];       // 26400 B
  __shared__ __align__(16) short rhb[NPG*RSTR];      // 13600 B (rh; later U)
  __shared__ __align__(16) short T1t[128*TSTR];      // 18432 B ([d][node]; XA preload + T)
  __shared__ __align__(16) short Mp[64*MSTR];        //  9216 B
  __shared__ int   rp[NPG+1];
  __shared__ short ci[2*EPG];
  __shared__ int   cnt[NPG];
  __shared__ int   stl[EPG];
  __shared__ float etl[EPG];
  __shared__ float ntl[NPG];
  __shared__ float disl[NPG];
  __shared__ float lvl[DD];
  __shared__ float srgl[DD];
  __shared__ float scl[NPG];
  __shared__ unsigned long long actm_s;
  __shared__ float red8[8];

  const int b = blockIdx.x, tid = threadIdx.x;
  const int nb = b*NPG, eb = b*EPG;
  const int wave = tid>>6, lane = tid&63, quad = lane>>4, l16 = lane&15;
  const float dtv = dtp[0];

  for (int i = tid; i < NPG*32; i += 512) {
    int n = i >> 5, dq = i & 31;
    ((float4*)(hl + n*HSTR))[dq] = ((const float4*)(x + (size_t)(nb+n)*128))[dq];
  }
  if (tid < EPG) { stl[tid] = (src[eb+tid]-nb) | ((dst[eb+tid]-nb)<<16); etl[tid] = edge_t[eb+tid]; }
  if (tid >= 64 && tid < 64+NPG) ntl[tid-64] = node_t[nb+tid-64];
  __syncthreads();

  // ---- static incidence CSR ----
  if (tid < NPG) {
    int c = 0;
    for (int e = 0; e < EPG; ++e) { int st=stl[e]; int s=st&0xffff, t=st>>16; c += (s==tid)+(t==tid); }
    cnt[tid] = c;
  }
  __syncthreads();
  if (tid == 0) { int a = 0; for (int n = 0; n < NPG; ++n) { rp[n] = a; a += cnt[n]; } rp[NPG] = a; }
  __syncthreads();
  if (tid < NPG) {
    int w = rp[tid];
    for (int e = 0; e < EPG; ++e) {
      int st = stl[e]; int s = st & 0xffff, t = st >> 16;
      if (t == tid) ci[w++] = (short)(s | (e<<8));
      if (s == tid) ci[w++] = (short)(t | (e<<8));
    }
  }
  __syncthreads();

  float zreg[4][4];

#define HW_PHASE(WT, XAOFS, USERH)                                                   \
  {                                                                                  \
    for (int i = tid; i < 64*16; i += 512) {                                         \
      int row = i >> 4, cq = i & 15;                                                 \
      int crow = (row > NPG-1) ? (NPG-1) : row;                                      \
      bfx8 v = *(const bfx8*)&XA[(size_t)(nb+crow)*384 + (XAOFS) + cq*8];            \
      _Pragma("unroll")                                                              \
      for (int j = 0; j < 8; ++j) T1t[(cq*8+j)*TSTR + row] = v[j];                   \
    }                                                                                \
    __syncthreads();                                                                 \
    f32x4 acc[4] = {{0.f,0.f,0.f,0.f},{0.f,0.f,0.f,0.f},{0.f,0.f,0.f,0.f},{0.f,0.f,0.f,0.f}}; \
    const int coln = wave*16 + l16;                                                  \
    _Pragma("unroll")                                                                \
    for (int k0 = 0; k0 < 128; k0 += 32) {                                           \
      bfx8 af[4];                                                                    \
      _Pragma("unroll")                                                              \
      for (int m = 0; m < 4; ++m) {                                                  \
        int arow = m*16 + l16; if (arow > NPG-1) arow = NPG-1;                       \
        if (USERH) {                                                                 \
          af[m] = *(const bfx8*)&rhb[arow*RSTR + k0 + quad*8];                       \
        } else {                                                                     \
          const float* hp = &hl[arow*HSTR + k0 + quad*8];                            \
          af[m] = pack8(*(const float4*)hp, *(const float4*)(hp+4));                 \
        }                                                                            \
      }                                                                              \
      bfx8 bfr = *(const bfx8*)&(WT)[(size_t)coln*128 + k0 + quad*8];                \
      _Pragma("unroll")                                                              \
      for (int m = 0; m < 4; ++m)                                                    \
        acc[m] = __builtin_amdgcn_mfma_f32_16x16x32_bf16(af[m], bfr, acc[m], 0, 0, 0); \
    }                                                                                \
    _Pragma("unroll")                                                                \
    for (int m = 0; m < 4; ++m)                                                      \
      _Pragma("unroll")                                                              \
      for (int r = 0; r < 4; ++r) {                                                  \
        int row = m*16 + quad*4 + r;                                                 \
        float v = acc[m][r] + bf2f(T1t[coln*TSTR + row]);                            \
        T1t[coln*TSTR + row] = f2bf(v);                                              \
      }                                                                              \
  }

#define AGG_PHASE(WHICH)                                                             \
  {                                                                                  \
    f32x4 acc[4] = {{0.f,0.f,0.f,0.f},{0.f,0.f,0.f,0.f},{0.f,0.f,0.f,0.f},{0.f,0.f,0.f,0.f}}; \
    const int cold = wave*16 + l16;                                                  \
    _Pragma("unroll")                                                                \
    for (int k0 = 0; k0 < 64; k0 += 32) {                                            \
      bfx8 af[4];                                                                    \
      _Pragma("unroll")                                                              \
      for (int m = 0; m < 4; ++m) af[m] = *(const bfx8*)&Mp[(m*16+l16)*MSTR + k0 + quad*8]; \
      bfx8 bfr = *(const bfx8*)&T1t[cold*TSTR + k0 + quad*8];                        \
      _Pragma("unroll")                                                              \
      for (int m = 0; m < 4; ++m)                                                    \
        acc[m] = __builtin_amdgcn_mfma_f32_16x16x32_bf16(af[m], bfr, acc[m], 0, 0, 0); \
    }                                                                                \
    if ((WHICH) == 0) {                                                              \
      float bb = brz[cold];                                                          \
      _Pragma("unroll")                                                              \
      for (int m = 0; m < 4; ++m)                                                    \
        _Pragma("unroll")                                                            \
        for (int r = 0; r < 4; ++r) {                                                \
          int row = m*16 + quad*4 + r;                                               \
          if (row < NPG) {                                                           \
            float s = sigmoidf_(acc[m][r] + bb);                                     \
            rhb[row*RSTR + cold] = f2bf(s * hl[row*HSTR + cold]);                    \
          }                                                                          \
        }                                                                            \
    } else if ((WHICH) == 1) {                                                       \
      float bb = brz[128 + cold];                                                    \
      _Pragma("unroll")                                                              \
      for (int m = 0; m < 4; ++m)                                                    \
        _Pragma("unroll")                                                            \
        for (int r = 0; r < 4; ++r)                                                  \
          zreg[m][r] = sigmoidf_(acc[m][r] + bb);                                    \
    } else {                                                                         \
      float bb = bu[cold];                                                           \
      _Pragma("unroll")                                                              \
      for (int m = 0; m < 4; ++m)                                                    \
        _Pragma("unroll")                                                            \
        for (int r = 0; r < 4; ++r) {                                                \
          int row = m*16 + quad*4 + r;                                               \
          if (row < NPG && ntl[row] >= t) {                                          \
            float hv = hl[row*HSTR + cold];                                          \
            float uu = tanhf(acc[m][r] + bb);                                        \
            hl[row*HSTR + cold] = hv + dtv*(1.f - zreg[m][r])*(uu - hv);             \
          }                                                                          \
        }                                                                            \
    }                                                                                \
  }

  for (int ks = 0; ks < NSPLITS; ++ks) {
    const float t = (float)ks * dtv;
    if (wave == 0) {
      bool p = false;
      if (lane < EPG) {
        int st = stl[lane]; int s = st & 0xffff, tt = st >> 16;
        p = (etl[lane] <= t) && (ntl[s] >= t) && (ntl[tt] >= t) && (s != tt);
      }
      unsigned long long m = __ballot(p);
      if (lane == 0) actm_s = m;
    }
    for (int i = tid; i < 64*MSTR/2; i += 512) ((int*)Mp)[i] = 0;
    __syncthreads();
    const unsigned long long actm = actm_s;
    if (tid < NPG) {
      float deg = 0.f;
      for (int idx = rp[tid]; idx < rp[tid+1]; ++idx)
        deg += (float)((actm >> (((int)ci[idx]) >> 8)) & 1ULL);
      disl[tid] = rsqrtf(fmaxf(deg, 1.f));
    }
    __syncthreads();
    if (tid < NPG) {
      float dn = disl[tid];
      for (int idx = rp[tid]; idx < rp[tid+1]; ++idx) {
        int v = ci[idx]; int j = v & 255, e = v >> 8;
        if ((actm >> e) & 1ULL)
          Mp[tid*MSTR + j] = f2bf(bf2f(Mp[tid*MSTR + j]) + dn*disl[j]);
      }
    }
    __syncthreads();

    HW_PHASE(Whrzt, 0, false);            __syncthreads();
    AGG_PHASE(0);                         __syncthreads();
    HW_PHASE(Whrzt + 128*128, 128, false);__syncthreads();
    AGG_PHASE(1);                         __syncthreads();
    HW_PHASE(Whht, 256, true);            __syncthreads();
    AGG_PHASE(2);                         __syncthreads();
  }
#undef HW_PHASE
#undef AGG_PHASE

  // ---- l2norm(h) in-place -> fb ----
  for (int rr0 = 0; rr0 < NPG; rr0 += 4) {
    const int r = rr0 + (tid>>7);
    const int d = tid & 127;
    float v = (r < NPG) ? hl[r*HSTR + d] : 0.f;
    float ss = v*v;
    for (int off=32; off; off>>=1) ss += __shfl_down(ss, off);
    if (lane == 0) red8[wave] = ss;
    __syncthreads();
    int g = tid>>7;
    float inv = 1.f/fmaxf(sqrtf(red8[2*g]+red8[2*g+1]), 1e-12f);
    if (r < NPG) hl[r*HSTR + d] = v*inv;
    __syncthreads();
  }

  // ---- U = fb @ Wu -> rhb (bf16) ----
  {
    f32x4 acc[4] = {{0.f,0.f,0.f,0.f},{0.f,0.f,0.f,0.f},{0.f,0.f,0.f,0.f},{0.f,0.f,0.f,0.f}};
    const int coln = wave*16 + l16;
#pragma unroll
    for (int k0 = 0; k0 < 128; k0 += 32) {
      bfx8 af[4];
#pragma unroll
      for (int m = 0; m < 4; ++m) {
        int arow = m*16 + l16; if (arow > NPG-1) arow = NPG-1;
        const float* hp = &hl[arow*HSTR + k0 + quad*8];
        af[m] = pack8(*(const float4*)hp, *(const float4*)(hp+4));
      }
      bfx8 bfr = *(const bfx8*)&Wut[(size_t)coln*128 + k0 + quad*8];
#pragma unroll
      for (int m = 0; m < 4; ++m)
        acc[m] = __builtin_amdgcn_mfma_f32_16x16x32_bf16(af[m], bfr, acc[m], 0, 0, 0);
    }
#pragma unroll
    for (int m = 0; m < 4; ++m)
#pragma unroll
      for (int r = 0; r < 4; ++r) {
        int row = m*16 + quad*4 + r;
        if (row < NPG) rhb[row*RSTR + coln] = f2bf(acc[m][r]);
      }
  }
  __syncthreads();
  // ---- lv = fb[last] @ Wv + bv ----
  if (tid < 128) {
    float a = bv[tid];
    for (int k = 0; k < 128; ++k) a += hl[(NPG-1)*HSTR + k] * bf2f(Wvt[(size_t)tid*128 + k]);
    lvl[tid] = a;
  }
  __syncthreads();
  // ---- scores e_i = sum_d We[d]*sigmoid(U[i,d]+lv[d]) ----
  for (int i = wave; i < NPG; i += 8) {
    int d0 = lane, d1 = lane + 64;
    float e = We_[d0]*sigmoidf_(bf2f(rhb[i*RSTR + d0]) + lvl[d0])
            + We_[d1]*sigmoidf_(bf2f(rhb[i*RSTR + d1]) + lvl[d1]);
    for (int off=32; off; off>>=1) e += __shfl_down(e, off);
    if (lane == 0) scl[i] = e;
  }
  __syncthreads();
  // ---- softmax over NPG (wave 0) ----
  if (wave == 0) {
    float v = (lane < NPG) ? scl[lane] : -1e30f;
    float m = v;
    for (int off=1; off<64; off<<=1) m = fmaxf(m, __shfl_xor(m, off));
    float ex = (lane < NPG) ? expf(v - m) : 0.f;
    float s = ex;
    for (int off=1; off<64; off<<=1) s += __shfl_xor(s, off);
    if (lane < NPG) scl[lane] = ex/s;
  }
  __syncthreads();
  // ---- sr_g = sum_i alpha_i fb[i,:] ----
  if (tid < 128) {
    float sg = 0.f;
    for (int i = 0; i < NPG; ++i) sg += hl[i*HSTR + tid] * scl[i];
    srgl[tid] = sg;
  }
  __syncthreads();
  // ---- sr = l2norm([last|sr_g] @ W_sr); srvb = bf16(FSCALE*sr) ----
  float accv = 0.f;
  if (tid < 128) {
    for (int k = 0; k < 128; ++k) accv += hl[(NPG-1)*HSTR + k] * W_sr[(size_t)k*128 + tid];
    for (int k = 0; k < 128; ++k) accv += srgl[k] * W_sr[(size_t)(128+k)*128 + tid];
    float ss = accv*accv;
    for (int off=32; off; off>>=1) ss += __shfl_down(ss, off);
    if (lane == 0) red8[wave] = ss;
  }
  __syncthreads();
  if (tid < 128) {
    float inv = 1.f/fmaxf(sqrtf(red8[0]+red8[1]), 1e-12f);
    srvb[(size_t)b*DD + tid] = f2bf(FSCALE*accv*inv);
  }
}

// ---------- bf16 MFMA GEMM: 64x64 block tile, 4 waves, 16x16x32 ----------
// modes: 0: C=A@B+bias fp32; 6: C=A@B bf16;
// 4: logits LSE partials (grid 8*NCB, XCD-swizzled); 5: out = acc - lse[row]
__global__ __launch_bounds__(256) void gemm_mfma(
    const short* __restrict__ A, int lda,
    const short* __restrict__ Bt, int ldbt,
    const float* __restrict__ bias,
    float* __restrict__ C, int ldc,
    int K, int mode,
    float* __restrict__ outp, float* __restrict__ pmax, float* __restrict__ psum)
{
  __shared__ short As[64*40];
  __shared__ short Bs[64*40];
  const int tid = threadIdx.x;
  const int wave = tid >> 6, lane = tid & 63;
  const int wr = wave >> 1, wc = wave & 1;
  const int quad = lane >> 4, l16 = lane & 15;
  int rb, cb;
  if (mode == 4 || mode == 5) {
    int t = (blockIdx.x & 7)*1563 + (blockIdx.x >> 3);   // 12504 = 8*1563
    rb = t & 7; cb = t >> 3;
  } else { rb = blockIdx.y; cb = blockIdx.x; }
  const int row0 = rb*64, col0 = cb*64;
  f32x4 acc[2][2] = {{{0.f,0.f,0.f,0.f},{0.f,0.f,0.f,0.f}},{{0.f,0.f,0.f,0.f},{0.f,0.f,0.f,0.f}}};
  const int sm = tid >> 2, skq = tid & 3;
  const short* Ap = A + (size_t)(row0+sm)*lda + skq*8;
  const short* Bp = Bt + (size_t)(col0+sm)*ldbt + skq*8;
  for (int k0 = 0; k0 < K; k0 += 32) {
    *(bfx8*)&As[sm*40 + skq*8] = *(const bfx8*)(Ap + k0);
    *(bfx8*)&Bs[sm*40 + skq*8] = *(const bfx8*)(Bp + k0);
    __syncthreads();
    bfx8 a0 = *(bfx8*)&As[(wr*32 + l16)*40 + quad*8];
    bfx8 a1 = *(bfx8*)&As[(wr*32 + 16 + l16)*40 + quad*8];
    bfx8 b0 = *(bfx8*)&Bs[(wc*32 + l16)*40 + quad*8];
    bfx8 b1 = *(bfx8*)&Bs[(wc*32 + 16 + l16)*40 + quad*8];
    acc[0][0] = __builtin_amdgcn_mfma_f32_16x16x32_bf16(a0, b0, acc[0][0], 0, 0, 0);
    acc[0][1] = __builtin_amdgcn_mfma_f32_16x16x32_bf16(a0, b1, acc[0][1], 0, 0, 0);
    acc[1][0] = __builtin_amdgcn_mfma_f32_16x16x32_bf16(a1, b0, acc[1][0], 0, 0, 0);
    acc[1][1] = __builtin_amdgcn_mfma_f32_16x16x32_bf16(a1, b1, acc[1][1], 0, 0, 0);
    __syncthreads();
  }

  if (mode == 0) {
#pragma unroll
    for (int i = 0; i < 2; ++i)
#pragma unroll
      for (int j = 0; j < 2; ++j) {
        int gc = col0 + wc*32 + j*16 + l16;
        float bb = bias ? bias[gc] : 0.f;
#pragma unroll
        for (int r = 0; r < 4; ++r) {
          int gr = row0 + wr*32 + i*16 + quad*4 + r;
          C[(size_t)gr*ldc + gc] = acc[i][j][r] + bb;
        }
      }
  } else if (mode == 6) {
    short* Cb = (short*)C;
#pragma unroll
    for (int i = 0; i < 2; ++i)
#pragma unroll
      for (int j = 0; j < 2; ++j) {
        int gc = col0 + wc*32 + j*16 + l16;
#pragma unroll
        for (int r = 0; r < 4; ++r) {
          int gr = row0 + wr*32 + i*16 + quad*4 + r;
          Cb[(size_t)gr*ldc + gc] = f2bf(acc[i][j][r]);
        }
      }
  } else if (mode == 4) {
    __shared__ float pm[64][2], ps[64][2];
    int c0 = col0 + wc*32 + l16;
    int c1 = c0 + 16;
#pragma unroll
    for (int i = 0; i < 2; ++i) {
#pragma unroll
      for (int r = 0; r < 4; ++r) {
        int rloc = wr*32 + i*16 + quad*4 + r;
        float v0 = (c0 < VV) ? acc[i][0][r] : -1e30f;
        float v1 = (c1 < VV) ? acc[i][1][r] : -1e30f;
        float m = fmaxf(v0, v1);
#pragma unroll
        for (int off = 1; off < 16; off <<= 1) m = fmaxf(m, __shfl_xor(m, off));
        float s = expf(v0 - m) + expf(v1 - m);
#pragma unroll
        for (int off = 1; off < 16; off <<= 1) s += __shfl_xor(s, off);
        if (l16 == 0) { pm[rloc][wc] = m; ps[rloc][wc] = s; }
      }
    }
    __syncthreads();
    if (tid < 64) {
      float m0 = pm[tid][0], m1 = pm[tid][1];
      float s0 = ps[tid][0], s1 = ps[tid][1];
      float M = fmaxf(m0, m1);
      float S = s0*expf(m0 - M) + s1*expf(m1 - M);
      pmax[(size_t)(row0 + tid)*NCB + cb] = M;
      psum[(size_t)(row0 + tid)*NCB + cb] = S;
    }
  } else { // mode 5
#pragma unroll
    for (int i = 0; i < 2; ++i) {
#pragma unroll
      for (int r = 0; r < 4; ++r) {
        int gr = row0 + wr*32 + i*16 + quad*4 + r;
        float l = bias[gr];
#pragma unroll
        for (int j = 0; j < 2; ++j) {
          int gc = col0 + wc*32 + j*16 + l16;
          if (gc < VV) outp[(size_t)gr*VV + gc] = acc[i][j][r] - l;
        }
      }
    }
  }
}

__global__ __launch_bounds__(256) void k_lse(const float* __restrict__ pmax, const float* __restrict__ psum,
                                             float* __restrict__ lse) {
  int r = blockIdx.x, tid = threadIdx.x;
  float m = -1e30f, s = 0.f;
  for (int cb = tid; cb < NCB; cb += 256) {
    float m2 = pmax[(size_t)r*NCB + cb], s2 = psum[(size_t)r*NCB + cb];
    float M = fmaxf(m, m2);
    s = s*expf(m - M) + s2*expf(m2 - M);
    m = M;
  }
  __shared__ float ms[256], ssh[256];
  ms[tid] = m; ssh[tid] = s; __syncthreads();
  for (int st=128; st; st>>=1) {
    if (tid < st) {
      float m2 = ms[tid+st], s2 = ssh[tid+st];
      float M = fmaxf(ms[tid], m2);
      ssh[tid] = ssh[tid]*expf(ms[tid]-M) + s2*expf(m2-M);
      ms[tid] = M;
    }
    __syncthreads();
  }
  if (tid==0) lse[r] = ms[0] + logf(ssh[0]);
}

extern "C" void kernel_launch(void* const* d_in, const int* in_sizes, int n_in,
                              void* d_out, int out_size, void* d_ws, size_t ws_size,
                              hipStream_t stream) {
  (void)in_sizes; (void)n_in; (void)out_size; (void)ws_size;
  const int*   iid    = (const int*)  d_in[0];
  const int*   src    = (const int*)  d_in[1];
  const int*   dst    = (const int*)  d_in[2];
  const float* edge_w = (const float*)d_in[3];
  const float* edge_t = (const float*)d_in[4];
  const float* node_t = (const float*)d_in[5];
  const float* emb    = (const float*)d_in[6];
  const float* W1     = (const float*)d_in[7];
  const float* W2     = (const float*)d_in[8];
  const float* gw_ih  = (const float*)d_in[9];
  const float* gw_hh  = (const float*)d_in[10];
  const float* gb_ih  = (const float*)d_in[11];
  const float* gb_hh  = (const float*)d_in[12];
  const float* Wxr = (const float*)d_in[13]; const float* bxr = (const float*)d_in[14];
  const float* Wxz = (const float*)d_in[15]; const float* bxz = (const float*)d_in[16];
  const float* Wxh = (const float*)d_in[17]; const float* bxh = (const float*)d_in[18];
  const float* Whr = (const float*)d_in[19]; const float* bhr = (const float*)d_in[20];
  const float* Whz = (const float*)d_in[21]; const float* bhz = (const float*)d_in[22];
  const float* Whh = (const float*)d_in[23]; const float* bhh = (const float*)d_in[24];
  const float* Wu  = (const float*)d_in[25];
  const float* Wv  = (const float*)d_in[26]; const float* bv  = (const float*)d_in[27];
  const float* We  = (const float*)d_in[28];
  const float* W_sr= (const float*)d_in[29];

  float* ws  = (float*)d_ws;
  float* out = (float*)d_out;

  // ---- workspace layout (float units) ----
  short* embn  = (short*)ws;                        // VPAD*128 sh = 6,402,048 fl
  float* pmax  = ws + 6402048;                      // 800,256
  float* psum  = pmax + 800256;                     // 800,256   -> 8,002,560
  short* M12t  = (short*)(ws + 8002560);            // 384*256 sh = 49,152 fl
  short* gwhhb = (short*)(ws + 8051712);            // 384*128 sh = 24,576 fl
  short* Whrzt = (short*)(ws + 8076288);            // 256*128 sh = 16,384 fl
  short* Whht  = (short*)(ws + 8092672);            // 128*128 sh =  8,192 fl
  short* W3t   = (short*)(ws + 8100864);            // 384*128 sh = 24,576 fl
  short* Wut   = (short*)(ws + 8125440);            //  8,192 fl
  short* Wvt   = (short*)(ws + 8133632);            //  8,192 fl
  float* brz   = ws + 8141824;                      // 256
  float* bu    = brz + 256;                         // 128
  float* dtp   = bu + 128;                          // 4
  float* lse   = dtp + 4;                           // 512
  short* srvb  = (short*)(lse + 512);               // 512*128 sh

  // ---- d_out as scratch until the logits pass (51.2M floats) ----
  short* ABb = (short*)out;                          // 25600*256 sh
  float* x   = out + (size_t) 4*1024*1024;           // 3.28M
  short* XA  = (short*)(out + (size_t) 8*1024*1024); // 25600*384 sh
  float* gi  = out + (size_t)20*1024*1024;           // 9.83M
  float* gh  = out + (size_t)30*1024*1024;           // 9.83M
  short* xb  = (short*)(out + (size_t)40*1024*1024); // 25600*128 sh
  short* xb2 = (short*)(out + (size_t)44*1024*1024); // 25600*128 sh

  // ---- prep (merged) ----
  k_prep<<<1090, 256, 0, stream>>>(W1, W2, gw_ih, gw_hh, Whr, Whz, Whh, Wxr, Wxz, Wxh, Wu, Wv,
      bxr, bhr, bxz, bhz, bxh, bhh, edge_t,
      M12t, gwhhb, Whrzt, Whht, W3t, Wut, Wvt, brz, bu, dtp);
  k_embn<<<VPAD/4, 256, 0, stream>>>(emb, embn);
  k_gather<<<NN, 128, 0, stream>>>(iid, emb, x, xb);

  // ---- stage C (MFMA form) ----
  k_grp_mean<<<BB, 512, 0, stream>>>(src, dst, edge_w, x, ABb);

  // ---- GRU ----
  gemm_mfma<<<dim3(6,400), 256, 0, stream>>>(ABb, 256, M12t, 256, gb_ih, gi, 384, 256, 0,
      nullptr, nullptr, nullptr);
  gemm_mfma<<<dim3(6,400), 256, 0, stream>>>(xb, 128, gwhhb, 128, gb_hh, gh, 384, 128, 0,
      nullptr, nullptr, nullptr);
  k_gru<<<NN, 128, 0, stream>>>(gi, gh, x, xb2);

  // ---- XA = x @ [Wxr|Wxz|Wxh] (bf16), split-invariant ----
  gemm_mfma<<<dim3(6,400), 256, 0, stream>>>(xb2, 128, W3t, 128, nullptr, (float*)XA, 384, 128, 6,
      nullptr, nullptr, nullptr);

  // ---- ODE + attention fused -> srvb ----
  k_ode_fused<<<BB, 512, 0, stream>>>(src, dst, edge_t, node_t, dtp, x, XA, Whrzt, Whht, brz, bu,
      Wut, Wvt, bv, We, W_sr, srvb);

  // ---- logits: pass 1 (LSE partials) -> lse -> pass 2 (store acc - lse) ----
  gemm_mfma<<<dim3(8*NCB), 256, 0, stream>>>(srvb, 128, embn, 128, nullptr, nullptr, 0, 128, 4,
      nullptr, pmax, psum);
  k_lse<<<BB, 256, 0, stream>>>(pmax, psum, lse);
  gemm_mfma<<<dim3(8*NCB), 256, 0, stream>>>(srvb, 128, embn, 128, lse, nullptr, 0, 128, 5,
      out, nullptr, nullptr);
}